// Round 1
// baseline (4247.629 us; speedup 1.0000x reference)
//
#include <hip/hip_runtime.h>

#define NN 100000

// ---------------- helpers ----------------
__device__ __forceinline__ void fma4(float4& a, float s, const float4& w) {
  a.x = fmaf(s, w.x, a.x);
  a.y = fmaf(s, w.y, a.y);
  a.z = fmaf(s, w.z, a.z);
  a.w = fmaf(s, w.w, a.w);
}

// Detect whether edge_index is stored as int64 (little-endian: odd words all 0
// since values < 100000) or int32. flag=1 -> int64, flag=0 -> int32.
__global__ void k_detect(const int* __restrict__ e, int* flag, int E) {
  if (threadIdx.x == 0 && blockIdx.x == 0) {
    int n = E < 64 ? E : 64;
    int m = 1;
    for (int i = 0; i < n; ++i) {
      if (e[2 * i + 1] != 0) { m = 0; break; }
    }
    *flag = m;
  }
}

__global__ void k_deg_init(float* deg) {
  int i = blockIdx.x * 256 + threadIdx.x;
  if (i < NN) deg[i] = 1.0f;  // self-loop
}

__global__ void k_deg_count(const int* __restrict__ e, const int* __restrict__ flag,
                            float* deg, int E) {
  int i = blockIdx.x * 256 + threadIdx.x;
  if (i >= E) return;
  int m = *flag;
  int d = m ? e[2 * (E + i)] : e[E + i];
  unsafeAtomicAdd(&deg[d], 1.0f);
}

__global__ void k_dinv(float* deg) {
  int i = blockIdx.x * 256 + threadIdx.x;
  if (i < NN) deg[i] = rsqrtf(deg[i]);
}

// C[M,N] = A[M,128] @ W[128,N], optional ReLU applied to A on load.
// Block: 256 threads. W fully staged in LDS. Each thread: 4 rows x 4 cols.
template <int N, bool RELU>
__global__ __launch_bounds__(256) void k_gemm(const float* __restrict__ A,
                                              const float* __restrict__ W,
                                              float* __restrict__ out, int M) {
  constexpr int K4 = 32;       // K=128 -> 32 float4 per row
  constexpr int N4 = N / 4;    // 32 or 16
  constexpr int CG = N4;       // channel groups
  constexpr int RQ = 256 / CG; // row quads per block
  constexpr int ROWS = RQ * 4; // 32 (N=128) or 64 (N=64)
  __shared__ float4 Wl[128 * N4];
  __shared__ float4 Xl[ROWS * K4];
  const int tid = threadIdx.x;
  const float4* W4 = (const float4*)W;
  for (int i = tid; i < 128 * N4; i += 256) Wl[i] = W4[i];
  const long long row0 = (long long)blockIdx.x * ROWS;
  const float4* A4 = (const float4*)A;
  for (int i = tid; i < ROWS * K4; i += 256) {
    int r = i >> 5;  // /K4
    long long row = row0 + r;
    float4 v = make_float4(0.f, 0.f, 0.f, 0.f);
    if (row < M) v = A4[row * K4 + (i & 31)];
    if (RELU) {
      v.x = fmaxf(v.x, 0.f); v.y = fmaxf(v.y, 0.f);
      v.z = fmaxf(v.z, 0.f); v.w = fmaxf(v.w, 0.f);
    }
    Xl[i] = v;
  }
  __syncthreads();
  const int c = tid % CG;
  const int rb = (tid / CG) * 4;
  float4 a0 = make_float4(0, 0, 0, 0), a1 = a0, a2 = a0, a3 = a0;
#pragma unroll 4
  for (int k4 = 0; k4 < K4; ++k4) {
    float4 w0 = Wl[(k4 * 4 + 0) * N4 + c];
    float4 w1 = Wl[(k4 * 4 + 1) * N4 + c];
    float4 w2 = Wl[(k4 * 4 + 2) * N4 + c];
    float4 w3 = Wl[(k4 * 4 + 3) * N4 + c];
    float4 x0 = Xl[(rb + 0) * K4 + k4];
    float4 x1 = Xl[(rb + 1) * K4 + k4];
    float4 x2 = Xl[(rb + 2) * K4 + k4];
    float4 x3 = Xl[(rb + 3) * K4 + k4];
    fma4(a0, x0.x, w0); fma4(a0, x0.y, w1); fma4(a0, x0.z, w2); fma4(a0, x0.w, w3);
    fma4(a1, x1.x, w0); fma4(a1, x1.y, w1); fma4(a1, x1.z, w2); fma4(a1, x1.w, w3);
    fma4(a2, x2.x, w0); fma4(a2, x2.y, w1); fma4(a2, x2.z, w2); fma4(a2, x2.w, w3);
    fma4(a3, x3.x, w0); fma4(a3, x3.y, w1); fma4(a3, x3.z, w2); fma4(a3, x3.w, w3);
  }
  float4* O4 = (float4*)out;
  long long row = row0 + rb;
  if (row + 0 < M) O4[(row + 0) * N4 + c] = a0;
  if (row + 1 < M) O4[(row + 1) * N4 + c] = a1;
  if (row + 2 < M) O4[(row + 2) * N4 + c] = a2;
  if (row + 3 < M) O4[(row + 3) * N4 + c] = a3;
}

// out[n][c] = h[n][c] * dinv[n]^2 + b[c]   (self-loop message + bias)
template <int C>
__global__ void k_self_bias(const float* __restrict__ h, const float* __restrict__ dinv,
                            const float* __restrict__ b, float* __restrict__ out) {
  constexpr int C4 = C / 4;
  int gid = blockIdx.x * 256 + threadIdx.x;
  if (gid >= NN * C4) return;
  int node = gid / C4;
  int cq = gid % C4;
  float di = dinv[node];
  float sc = di * di;
  float4 v = ((const float4*)h)[gid];
  float4 bb = ((const float4*)b)[cq];
  float4 o;
  o.x = fmaf(v.x, sc, bb.x);
  o.y = fmaf(v.y, sc, bb.y);
  o.z = fmaf(v.z, sc, bb.z);
  o.w = fmaf(v.w, sc, bb.w);
  ((float4*)out)[gid] = o;
}

// out[dst] += h[src] * dinv[src]*dinv[dst], C/4 threads per edge
template <int C>
__global__ void k_scatter(const int* __restrict__ e, const int* __restrict__ flag,
                          const float* __restrict__ dinv, const float* __restrict__ h,
                          float* __restrict__ out, int E) {
  constexpr int TPE = C / 4;
  long long gid = (long long)blockIdx.x * blockDim.x + threadIdx.x;
  int ei = (int)(gid / TPE);
  int cq = (int)(gid % TPE);
  if (ei >= E) return;
  int m = *flag;
  int s, d;
  if (m) { s = e[2 * ei]; d = e[2 * (E + ei)]; }
  else   { s = e[ei];     d = e[E + ei]; }
  float nrm = dinv[s] * dinv[d];
  float4 v = ((const float4*)h)[(long long)s * TPE + cq];
  float* op = out + (long long)d * C + (long long)cq * 4;
  unsafeAtomicAdd(op + 0, v.x * nrm);
  unsafeAtomicAdd(op + 1, v.y * nrm);
  unsafeAtomicAdd(op + 2, v.z * nrm);
  unsafeAtomicAdd(op + 3, v.w * nrm);
}

extern "C" void kernel_launch(void* const* d_in, const int* in_sizes, int n_in,
                              void* d_out, int out_size, void* d_ws, size_t ws_size,
                              hipStream_t stream) {
  const float* x  = (const float*)d_in[0];
  const int*   e  = (const int*)d_in[1];
  const float* W1 = (const float*)d_in[2];
  const float* b1 = (const float*)d_in[3];
  const float* W2 = (const float*)d_in[4];
  const float* b2 = (const float*)d_in[5];
  float* out = (float*)d_out;
  const int E = in_sizes[1] / 2;

  char* ws = (char*)d_ws;
  float* dinv = (float*)ws;                              // 400,000 B
  int*   flag = (int*)(ws + 400000);                     // 4 B
  float* h    = (float*)(ws + (1 << 20));                // 51.2 MB (reused as h2)
  float* out1 = (float*)(ws + (1 << 20) + 51200000);     // 51.2 MB
  // total workspace use: ~98.7 MiB

  k_detect<<<1, 64, 0, stream>>>(e, flag, E);
  k_deg_init<<<(NN + 255) / 256, 256, 0, stream>>>(dinv);
  k_deg_count<<<(E + 255) / 256, 256, 0, stream>>>(e, flag, dinv, E);
  k_dinv<<<(NN + 255) / 256, 256, 0, stream>>>(dinv);

  // layer 1: h = x@W1 ; out1 = scatter(h) + self + b1
  k_gemm<128, false><<<(NN + 31) / 32, 256, 0, stream>>>(x, W1, h, NN);
  k_self_bias<128><<<(NN * 32 + 255) / 256, 256, 0, stream>>>(h, dinv, b1, out1);
  {
    long long tot = (long long)E * 32;
    k_scatter<128><<<(int)((tot + 255) / 256), 256, 0, stream>>>(e, flag, dinv, h, out1, E);
  }

  // layer 2: h2 = relu(out1)@W2 ; d_out = scatter(h2) + self + b2
  k_gemm<64, true><<<(NN + 63) / 64, 256, 0, stream>>>(out1, W2, h, NN);
  k_self_bias<64><<<(NN * 16 + 255) / 256, 256, 0, stream>>>(h, dinv, b2, out);
  {
    long long tot = (long long)E * 16;
    k_scatter<64><<<(int)((tot + 255) / 256), 256, 0, stream>>>(e, flag, dinv, h, out, E);
  }
}

// Round 2
// 729.246 us; speedup vs baseline: 5.8247x; 5.8247x over previous
//
#include <hip/hip_runtime.h>

#define NN 100000

// ---------------- helpers ----------------
__device__ __forceinline__ void fma4(float4& a, float s, const float4& w) {
  a.x = fmaf(s, w.x, a.x);
  a.y = fmaf(s, w.y, a.y);
  a.z = fmaf(s, w.z, a.z);
  a.w = fmaf(s, w.w, a.w);
}

// Detect whether edge_index is stored as int64 (little-endian: odd words all 0
// since values < 100000) or int32. flag=1 -> int64, flag=0 -> int32.
__global__ void k_detect(const int* __restrict__ e, int* flag, int E) {
  if (threadIdx.x == 0 && blockIdx.x == 0) {
    int n = E < 64 ? E : 64;
    int m = 1;
    for (int i = 0; i < n; ++i) {
      if (e[2 * i + 1] != 0) { m = 0; break; }
    }
    *flag = m;
  }
}

__global__ void k_zero_i32(int* p, int n) {
  int i = blockIdx.x * 256 + threadIdx.x;
  if (i < n) p[i] = 0;
}

__global__ void k_deg_count(const int* __restrict__ e, const int* __restrict__ flag,
                            int* __restrict__ deg, int E) {
  int i = blockIdx.x * 256 + threadIdx.x;
  if (i >= E) return;
  int m = *flag;
  int d = m ? e[2 * (E + i)] : e[E + i];
  atomicAdd(&deg[d], 1);
}

// dinv[i] = rsqrt(deg[i] + 1)   (+1 = self loop)
__global__ void k_dinv(const int* __restrict__ deg, float* __restrict__ dinv) {
  int i = blockIdx.x * 256 + threadIdx.x;
  if (i < NN) dinv[i] = rsqrtf((float)(deg[i] + 1));
}

// Single-block chunked exclusive scan of deg[0..NN) -> rowptr, cursor.
__global__ __launch_bounds__(1024) void k_scan(const int* __restrict__ deg,
                                               int* __restrict__ rowptr,
                                               int* __restrict__ cursor) {
  __shared__ int buf[1024];
  __shared__ int carry_s;
  int tid = threadIdx.x;
  if (tid == 0) carry_s = 0;
  __syncthreads();
  for (int base = 0; base < NN; base += 1024) {
    int i = base + tid;
    int v = (i < NN) ? deg[i] : 0;
    buf[tid] = v;
    __syncthreads();
#pragma unroll
    for (int off = 1; off < 1024; off <<= 1) {
      int t = (tid >= off) ? buf[tid - off] : 0;
      __syncthreads();
      buf[tid] += t;
      __syncthreads();
    }
    int incl = buf[tid];
    int carry = carry_s;
    if (i < NN) {
      int excl = carry + incl - v;
      rowptr[i] = excl;
      cursor[i] = excl;
    }
    __syncthreads();
    if (tid == 1023) carry_s = carry + incl;
    __syncthreads();
  }
  if (tid == 0) rowptr[NN] = carry_s;
}

// Bucket edges by dst: srcs[rowptr[d] ...] = list of srcs into d.
__global__ void k_fill(const int* __restrict__ e, const int* __restrict__ flag,
                       int* __restrict__ cursor, int* __restrict__ srcs, int E) {
  int i = blockIdx.x * 256 + threadIdx.x;
  if (i >= E) return;
  int m = *flag;
  int s, d;
  if (m) { s = e[2 * i]; d = e[2 * (E + i)]; }
  else   { s = e[i];     d = e[E + i]; }
  int p = atomicAdd(&cursor[d], 1);
  srcs[p] = s;
}

// Gather-reduce per node: out[d] = dinv[d]*(sum_{s in in(d)} dinv[s]*h[s]
//                                           + dinv[d]*h[d]) + b
// 64*4/C nodes per wave, C/4 lanes per node (float4 per lane).
template <int C>
__global__ __launch_bounds__(256) void k_gather(const int* __restrict__ rowptr,
                                                const int* __restrict__ srcs,
                                                const float* __restrict__ dinv,
                                                const float* __restrict__ h,
                                                const float* __restrict__ b,
                                                float* __restrict__ out) {
  constexpr int C4 = C / 4;       // float4 per row
  constexpr int LPN = C4;         // lanes per node
  constexpr int NPW = 64 / LPN;   // nodes per wave
  constexpr int NPB = NPW * 4;    // nodes per block (4 waves)
  const int wave = threadIdx.x >> 6;
  const int lane = threadIdx.x & 63;
  const int grp = lane / LPN;
  const int li = lane % LPN;
  const int node = blockIdx.x * NPB + wave * NPW + grp;
  if (node >= NN) return;
  const float dd = dinv[node];
  const float4* h4 = (const float4*)h;
  float4 hv = h4[(long long)node * C4 + li];
  float4 acc = make_float4(dd * hv.x, dd * hv.y, dd * hv.z, dd * hv.w);
  const int beg = rowptr[node], end = rowptr[node + 1];
  for (int e = beg; e < end; ++e) {
    int s = srcs[e];
    float w = dinv[s];
    float4 v = h4[(long long)s * C4 + li];
    fma4(acc, w, v);
  }
  float4 bb = ((const float4*)b)[li];
  float4 o;
  o.x = fmaf(dd, acc.x, bb.x);
  o.y = fmaf(dd, acc.y, bb.y);
  o.z = fmaf(dd, acc.z, bb.z);
  o.w = fmaf(dd, acc.w, bb.w);
  ((float4*)out)[(long long)node * C4 + li] = o;
}

// C[M,N] = A[M,128] @ W[128,N], optional ReLU applied to A on load.
template <int N, bool RELU>
__global__ __launch_bounds__(256) void k_gemm(const float* __restrict__ A,
                                              const float* __restrict__ W,
                                              float* __restrict__ out, int M) {
  constexpr int K4 = 32;
  constexpr int N4 = N / 4;
  constexpr int CG = N4;
  constexpr int RQ = 256 / CG;
  constexpr int ROWS = RQ * 4;
  __shared__ float4 Wl[128 * N4];
  __shared__ float4 Xl[ROWS * K4];
  const int tid = threadIdx.x;
  const float4* W4 = (const float4*)W;
  for (int i = tid; i < 128 * N4; i += 256) Wl[i] = W4[i];
  const long long row0 = (long long)blockIdx.x * ROWS;
  const float4* A4 = (const float4*)A;
  for (int i = tid; i < ROWS * K4; i += 256) {
    int r = i >> 5;
    long long row = row0 + r;
    float4 v = make_float4(0.f, 0.f, 0.f, 0.f);
    if (row < M) v = A4[row * K4 + (i & 31)];
    if (RELU) {
      v.x = fmaxf(v.x, 0.f); v.y = fmaxf(v.y, 0.f);
      v.z = fmaxf(v.z, 0.f); v.w = fmaxf(v.w, 0.f);
    }
    Xl[i] = v;
  }
  __syncthreads();
  const int c = tid % CG;
  const int rb = (tid / CG) * 4;
  float4 a0 = make_float4(0, 0, 0, 0), a1 = a0, a2 = a0, a3 = a0;
#pragma unroll 4
  for (int k4 = 0; k4 < K4; ++k4) {
    float4 w0 = Wl[(k4 * 4 + 0) * N4 + c];
    float4 w1 = Wl[(k4 * 4 + 1) * N4 + c];
    float4 w2 = Wl[(k4 * 4 + 2) * N4 + c];
    float4 w3 = Wl[(k4 * 4 + 3) * N4 + c];
    float4 x0 = Xl[(rb + 0) * K4 + k4];
    float4 x1 = Xl[(rb + 1) * K4 + k4];
    float4 x2 = Xl[(rb + 2) * K4 + k4];
    float4 x3 = Xl[(rb + 3) * K4 + k4];
    fma4(a0, x0.x, w0); fma4(a0, x0.y, w1); fma4(a0, x0.z, w2); fma4(a0, x0.w, w3);
    fma4(a1, x1.x, w0); fma4(a1, x1.y, w1); fma4(a1, x1.z, w2); fma4(a1, x1.w, w3);
    fma4(a2, x2.x, w0); fma4(a2, x2.y, w1); fma4(a2, x2.z, w2); fma4(a2, x2.w, w3);
    fma4(a3, x3.x, w0); fma4(a3, x3.y, w1); fma4(a3, x3.z, w2); fma4(a3, x3.w, w3);
  }
  float4* O4 = (float4*)out;
  long long row = row0 + rb;
  if (row + 0 < M) O4[(row + 0) * N4 + c] = a0;
  if (row + 1 < M) O4[(row + 1) * N4 + c] = a1;
  if (row + 2 < M) O4[(row + 2) * N4 + c] = a2;
  if (row + 3 < M) O4[(row + 3) * N4 + c] = a3;
}

// ---------------- fallback (atomic scatter) kernels ----------------
template <int C>
__global__ void k_self_bias(const float* __restrict__ h, const float* __restrict__ dinv,
                            const float* __restrict__ b, float* __restrict__ out) {
  constexpr int C4 = C / 4;
  int gid = blockIdx.x * 256 + threadIdx.x;
  if (gid >= NN * C4) return;
  int node = gid / C4;
  int cq = gid % C4;
  float di = dinv[node];
  float sc = di * di;
  float4 v = ((const float4*)h)[gid];
  float4 bb = ((const float4*)b)[cq];
  float4 o;
  o.x = fmaf(v.x, sc, bb.x);
  o.y = fmaf(v.y, sc, bb.y);
  o.z = fmaf(v.z, sc, bb.z);
  o.w = fmaf(v.w, sc, bb.w);
  ((float4*)out)[gid] = o;
}

template <int C>
__global__ void k_scatter(const int* __restrict__ e, const int* __restrict__ flag,
                          const float* __restrict__ dinv, const float* __restrict__ h,
                          float* __restrict__ out, int E) {
  constexpr int TPE = C / 4;
  long long gid = (long long)blockIdx.x * blockDim.x + threadIdx.x;
  int ei = (int)(gid / TPE);
  int cq = (int)(gid % TPE);
  if (ei >= E) return;
  int m = *flag;
  int s, d;
  if (m) { s = e[2 * ei]; d = e[2 * (E + ei)]; }
  else   { s = e[ei];     d = e[E + ei]; }
  float nrm = dinv[s] * dinv[d];
  float4 v = ((const float4*)h)[(long long)s * TPE + cq];
  float* op = out + (long long)d * C + (long long)cq * 4;
  unsafeAtomicAdd(op + 0, v.x * nrm);
  unsafeAtomicAdd(op + 1, v.y * nrm);
  unsafeAtomicAdd(op + 2, v.z * nrm);
  unsafeAtomicAdd(op + 3, v.w * nrm);
}

extern "C" void kernel_launch(void* const* d_in, const int* in_sizes, int n_in,
                              void* d_out, int out_size, void* d_ws, size_t ws_size,
                              hipStream_t stream) {
  const float* x  = (const float*)d_in[0];
  const int*   e  = (const int*)d_in[1];
  const float* W1 = (const float*)d_in[2];
  const float* b1 = (const float*)d_in[3];
  const float* W2 = (const float*)d_in[4];
  const float* b2 = (const float*)d_in[5];
  float* out = (float*)d_out;
  const int E = in_sizes[1] / 2;

  char* ws = (char*)d_ws;
  // CSR-path layout (bytes):
  const size_t o_dinv   = 0;                       // 400,000
  const size_t o_flag   = 400000;                  // 16
  const size_t o_deg    = 400016;                  // 400,000
  const size_t o_rowptr = 800016;                  // 400,004 (NN+1)
  const size_t o_cursor = 1200032;                 // 400,000
  const size_t o_srcs   = 1600032;                 // 4*E = 6,400,000
  const size_t o_h      = 8000032;                 // 51,200,000
  const size_t o_out1   = 59200032;                // 51,200,000
  const size_t need_csr = 110400032;

  float* dinv   = (float*)(ws + o_dinv);
  int*   flag   = (int*)(ws + o_flag);
  int*   deg    = (int*)(ws + o_deg);
  int*   rowptr = (int*)(ws + o_rowptr);
  int*   cursor = (int*)(ws + o_cursor);
  int*   srcs   = (int*)(ws + o_srcs);
  float* h      = (float*)(ws + o_h);
  float* out1   = (float*)(ws + o_out1);

  k_detect<<<1, 64, 0, stream>>>(e, flag, E);
  k_zero_i32<<<(NN + 255) / 256, 256, 0, stream>>>(deg, NN);
  k_deg_count<<<(E + 255) / 256, 256, 0, stream>>>(e, flag, deg, E);
  k_dinv<<<(NN + 255) / 256, 256, 0, stream>>>(deg, dinv);

  if (ws_size >= need_csr) {
    // ---- CSR gather path ----
    k_scan<<<1, 1024, 0, stream>>>(deg, rowptr, cursor);
    k_fill<<<(E + 255) / 256, 256, 0, stream>>>(e, flag, cursor, srcs, E);

    k_gemm<128, false><<<(NN + 31) / 32, 256, 0, stream>>>(x, W1, h, NN);
    k_gather<128><<<(NN + 7) / 8, 256, 0, stream>>>(rowptr, srcs, dinv, h, b1, out1);

    k_gemm<64, true><<<(NN + 63) / 64, 256, 0, stream>>>(out1, W2, h, NN);
    k_gather<64><<<(NN + 15) / 16, 256, 0, stream>>>(rowptr, srcs, dinv, h, b2, out);
  } else {
    // ---- fallback: atomic scatter path (fits in ~103 MB) ----
    float* hF    = (float*)(ws + (1 << 20));
    float* out1F = (float*)(ws + (1 << 20) + 51200000);
    k_gemm<128, false><<<(NN + 31) / 32, 256, 0, stream>>>(x, W1, hF, NN);
    k_self_bias<128><<<(NN * 32 + 255) / 256, 256, 0, stream>>>(hF, dinv, b1, out1F);
    long long tot1 = (long long)E * 32;
    k_scatter<128><<<(int)((tot1 + 255) / 256), 256, 0, stream>>>(e, flag, dinv, hF, out1F, E);
    k_gemm<64, true><<<(NN + 63) / 64, 256, 0, stream>>>(out1F, W2, hF, NN);
    k_self_bias<64><<<(NN * 16 + 255) / 256, 256, 0, stream>>>(hF, dinv, b2, out);
    long long tot2 = (long long)E * 16;
    k_scatter<64><<<(int)((tot2 + 255) / 256), 256, 0, stream>>>(e, flag, dinv, hF, out, E);
  }
}

// Round 3
// 539.605 us; speedup vs baseline: 7.8717x; 1.3514x over previous
//
#include <hip/hip_runtime.h>

#define NN 100000

// ---------------- helpers ----------------
__device__ __forceinline__ void fma4(float4& a, float s, const float4& w) {
  a.x = fmaf(s, w.x, a.x);
  a.y = fmaf(s, w.y, a.y);
  a.z = fmaf(s, w.z, a.z);
  a.w = fmaf(s, w.w, a.w);
}

// Detect whether edge_index is stored as int64 (little-endian: odd words all 0
// since values < 100000) or int32. flag=1 -> int64, flag=0 -> int32.
__global__ void k_detect(const int* __restrict__ e, int* flag, int E) {
  if (threadIdx.x == 0 && blockIdx.x == 0) {
    int n = E < 64 ? E : 64;
    int m = 1;
    for (int i = 0; i < n; ++i) {
      if (e[2 * i + 1] != 0) { m = 0; break; }
    }
    *flag = m;
  }
}

__global__ void k_zero_i32(int* p, int n) {
  int i = blockIdx.x * 256 + threadIdx.x;
  if (i < n) p[i] = 0;
}

__global__ void k_deg_count(const int* __restrict__ e, const int* __restrict__ flag,
                            int* __restrict__ deg, int E) {
  int i = blockIdx.x * 256 + threadIdx.x;
  if (i >= E) return;
  int m = *flag;
  int d = m ? e[2 * (E + i)] : e[E + i];
  atomicAdd(&deg[d], 1);
}

// dinv[i] = rsqrt(deg[i] + 1)   (+1 = self loop)
__global__ void k_dinv(const int* __restrict__ deg, float* __restrict__ dinv) {
  int i = blockIdx.x * 256 + threadIdx.x;
  if (i < NN) dinv[i] = rsqrtf((float)(deg[i] + 1));
}

// ---------------- hierarchical scan (3 kernels) ----------------
// Pass 1: each block scans a 1024-int chunk (256 thr x 4), writes the local
// EXCLUSIVE scan into rowptr[] and its chunk total into bsum[b].
__global__ __launch_bounds__(256) void k_scan_part(const int* __restrict__ deg,
                                                   int* __restrict__ rowptr,
                                                   int* __restrict__ bsum) {
  __shared__ int s[256];
  const int tid = threadIdx.x;
  const int base = blockIdx.x * 1024 + tid * 4;
  int v0 = (base + 0 < NN) ? deg[base + 0] : 0;
  int v1 = (base + 1 < NN) ? deg[base + 1] : 0;
  int v2 = (base + 2 < NN) ? deg[base + 2] : 0;
  int v3 = (base + 3 < NN) ? deg[base + 3] : 0;
  int tsum = v0 + v1 + v2 + v3;
  s[tid] = tsum;
  __syncthreads();
#pragma unroll
  for (int off = 1; off < 256; off <<= 1) {
    int t = (tid >= off) ? s[tid - off] : 0;
    __syncthreads();
    s[tid] += t;
    __syncthreads();
  }
  int p = s[tid] - tsum;  // exclusive prefix of this thread's quad
  if (tid == 255) bsum[blockIdx.x] = s[255];
  if (base + 0 < NN) rowptr[base + 0] = p; p += v0;
  if (base + 1 < NN) rowptr[base + 1] = p; p += v1;
  if (base + 2 < NN) rowptr[base + 2] = p; p += v2;
  if (base + 3 < NN) rowptr[base + 3] = p;
}

// Pass 2: single block exclusive-scans bsum[0..nb) (nb <= 256), total -> *total.
__global__ __launch_bounds__(256) void k_scan_mid(int* __restrict__ bsum, int nb,
                                                  int* __restrict__ total) {
  __shared__ int s[256];
  const int tid = threadIdx.x;
  int v = (tid < nb) ? bsum[tid] : 0;
  s[tid] = v;
  __syncthreads();
#pragma unroll
  for (int off = 1; off < 256; off <<= 1) {
    int t = (tid >= off) ? s[tid - off] : 0;
    __syncthreads();
    s[tid] += t;
    __syncthreads();
  }
  if (tid < nb) bsum[tid] = s[tid] - v;  // exclusive
  if (tid == 255) *total = s[255];
}

// Pass 3: add block offsets; produce final rowptr and cursor copy.
__global__ void k_scan_add(int* __restrict__ rowptr, const int* __restrict__ bsum,
                           const int* __restrict__ total, int* __restrict__ cursor) {
  int i = blockIdx.x * 256 + threadIdx.x;
  if (i < NN) {
    int v = rowptr[i] + bsum[i >> 10];
    rowptr[i] = v;
    cursor[i] = v;
  } else if (i == NN) {
    rowptr[NN] = *total;
  }
}

// Bucket edges by dst: srcs[rowptr[d] ...] = list of srcs into d.
__global__ void k_fill(const int* __restrict__ e, const int* __restrict__ flag,
                       int* __restrict__ cursor, int* __restrict__ srcs, int E) {
  int i = blockIdx.x * 256 + threadIdx.x;
  if (i >= E) return;
  int m = *flag;
  int s, d;
  if (m) { s = e[2 * i]; d = e[2 * (E + i)]; }
  else   { s = e[i];     d = e[E + i]; }
  int p = atomicAdd(&cursor[d], 1);
  srcs[p] = s;
}

// Gather-reduce per node: out[d] = dinv[d]*(sum_{s in in(d)} dinv[s]*h[s]
//                                           + dinv[d]*h[d]) + b
template <int C>
__global__ __launch_bounds__(256) void k_gather(const int* __restrict__ rowptr,
                                                const int* __restrict__ srcs,
                                                const float* __restrict__ dinv,
                                                const float* __restrict__ h,
                                                const float* __restrict__ b,
                                                float* __restrict__ out) {
  constexpr int C4 = C / 4;       // float4 per row
  constexpr int LPN = C4;         // lanes per node
  constexpr int NPW = 64 / LPN;   // nodes per wave
  constexpr int NPB = NPW * 4;    // nodes per block (4 waves)
  const int wave = threadIdx.x >> 6;
  const int lane = threadIdx.x & 63;
  const int grp = lane / LPN;
  const int li = lane % LPN;
  const int node = blockIdx.x * NPB + wave * NPW + grp;
  if (node >= NN) return;
  const float dd = dinv[node];
  const float4* h4 = (const float4*)h;
  float4 hv = h4[(long long)node * C4 + li];
  float4 acc = make_float4(dd * hv.x, dd * hv.y, dd * hv.z, dd * hv.w);
  const int beg = rowptr[node], end = rowptr[node + 1];
  int e = beg;
  for (; e + 2 <= end; e += 2) {
    int s0 = srcs[e], s1 = srcs[e + 1];
    float w0 = dinv[s0], w1 = dinv[s1];
    float4 u0 = h4[(long long)s0 * C4 + li];
    float4 u1 = h4[(long long)s1 * C4 + li];
    fma4(acc, w0, u0);
    fma4(acc, w1, u1);
  }
  if (e < end) {
    int s0 = srcs[e];
    float w0 = dinv[s0];
    float4 u0 = h4[(long long)s0 * C4 + li];
    fma4(acc, w0, u0);
  }
  float4 bb = ((const float4*)b)[li];
  float4 o;
  o.x = fmaf(dd, acc.x, bb.x);
  o.y = fmaf(dd, acc.y, bb.y);
  o.z = fmaf(dd, acc.z, bb.z);
  o.w = fmaf(dd, acc.w, bb.w);
  ((float4*)out)[(long long)node * C4 + li] = o;
}

// C[M,N] = A[M,128] @ W[128,N], optional ReLU applied to A on load.
template <int N, bool RELU>
__global__ __launch_bounds__(256) void k_gemm(const float* __restrict__ A,
                                              const float* __restrict__ W,
                                              float* __restrict__ out, int M) {
  constexpr int K4 = 32;
  constexpr int N4 = N / 4;
  constexpr int CG = N4;
  constexpr int RQ = 256 / CG;
  constexpr int ROWS = RQ * 4;
  __shared__ float4 Wl[128 * N4];
  __shared__ float4 Xl[ROWS * K4];
  const int tid = threadIdx.x;
  const float4* W4 = (const float4*)W;
  for (int i = tid; i < 128 * N4; i += 256) Wl[i] = W4[i];
  const long long row0 = (long long)blockIdx.x * ROWS;
  const float4* A4 = (const float4*)A;
  for (int i = tid; i < ROWS * K4; i += 256) {
    int r = i >> 5;
    long long row = row0 + r;
    float4 v = make_float4(0.f, 0.f, 0.f, 0.f);
    if (row < M) v = A4[row * K4 + (i & 31)];
    if (RELU) {
      v.x = fmaxf(v.x, 0.f); v.y = fmaxf(v.y, 0.f);
      v.z = fmaxf(v.z, 0.f); v.w = fmaxf(v.w, 0.f);
    }
    Xl[i] = v;
  }
  __syncthreads();
  const int c = tid % CG;
  const int rb = (tid / CG) * 4;
  float4 a0 = make_float4(0, 0, 0, 0), a1 = a0, a2 = a0, a3 = a0;
#pragma unroll 4
  for (int k4 = 0; k4 < K4; ++k4) {
    float4 w0 = Wl[(k4 * 4 + 0) * N4 + c];
    float4 w1 = Wl[(k4 * 4 + 1) * N4 + c];
    float4 w2 = Wl[(k4 * 4 + 2) * N4 + c];
    float4 w3 = Wl[(k4 * 4 + 3) * N4 + c];
    float4 x0 = Xl[(rb + 0) * K4 + k4];
    float4 x1 = Xl[(rb + 1) * K4 + k4];
    float4 x2 = Xl[(rb + 2) * K4 + k4];
    float4 x3 = Xl[(rb + 3) * K4 + k4];
    fma4(a0, x0.x, w0); fma4(a0, x0.y, w1); fma4(a0, x0.z, w2); fma4(a0, x0.w, w3);
    fma4(a1, x1.x, w0); fma4(a1, x1.y, w1); fma4(a1, x1.z, w2); fma4(a1, x1.w, w3);
    fma4(a2, x2.x, w0); fma4(a2, x2.y, w1); fma4(a2, x2.z, w2); fma4(a2, x2.w, w3);
    fma4(a3, x3.x, w0); fma4(a3, x3.y, w1); fma4(a3, x3.z, w2); fma4(a3, x3.w, w3);
  }
  float4* O4 = (float4*)out;
  long long row = row0 + rb;
  if (row + 0 < M) O4[(row + 0) * N4 + c] = a0;
  if (row + 1 < M) O4[(row + 1) * N4 + c] = a1;
  if (row + 2 < M) O4[(row + 2) * N4 + c] = a2;
  if (row + 3 < M) O4[(row + 3) * N4 + c] = a3;
}

// ---------------- fallback (atomic scatter) kernels ----------------
template <int C>
__global__ void k_self_bias(const float* __restrict__ h, const float* __restrict__ dinv,
                            const float* __restrict__ b, float* __restrict__ out) {
  constexpr int C4 = C / 4;
  int gid = blockIdx.x * 256 + threadIdx.x;
  if (gid >= NN * C4) return;
  int node = gid / C4;
  int cq = gid % C4;
  float di = dinv[node];
  float sc = di * di;
  float4 v = ((const float4*)h)[gid];
  float4 bb = ((const float4*)b)[cq];
  float4 o;
  o.x = fmaf(v.x, sc, bb.x);
  o.y = fmaf(v.y, sc, bb.y);
  o.z = fmaf(v.z, sc, bb.z);
  o.w = fmaf(v.w, sc, bb.w);
  ((float4*)out)[gid] = o;
}

template <int C>
__global__ void k_scatter(const int* __restrict__ e, const int* __restrict__ flag,
                          const float* __restrict__ dinv, const float* __restrict__ h,
                          float* __restrict__ out, int E) {
  constexpr int TPE = C / 4;
  long long gid = (long long)blockIdx.x * blockDim.x + threadIdx.x;
  int ei = (int)(gid / TPE);
  int cq = (int)(gid % TPE);
  if (ei >= E) return;
  int m = *flag;
  int s, d;
  if (m) { s = e[2 * ei]; d = e[2 * (E + ei)]; }
  else   { s = e[ei];     d = e[E + ei]; }
  float nrm = dinv[s] * dinv[d];
  float4 v = ((const float4*)h)[(long long)s * TPE + cq];
  float* op = out + (long long)d * C + (long long)cq * 4;
  unsafeAtomicAdd(op + 0, v.x * nrm);
  unsafeAtomicAdd(op + 1, v.y * nrm);
  unsafeAtomicAdd(op + 2, v.z * nrm);
  unsafeAtomicAdd(op + 3, v.w * nrm);
}

extern "C" void kernel_launch(void* const* d_in, const int* in_sizes, int n_in,
                              void* d_out, int out_size, void* d_ws, size_t ws_size,
                              hipStream_t stream) {
  const float* x  = (const float*)d_in[0];
  const int*   e  = (const int*)d_in[1];
  const float* W1 = (const float*)d_in[2];
  const float* b1 = (const float*)d_in[3];
  const float* W2 = (const float*)d_in[4];
  const float* b2 = (const float*)d_in[5];
  float* out = (float*)d_out;
  const int E = in_sizes[1] / 2;

  char* ws = (char*)d_ws;
  // CSR-path layout (bytes):
  const size_t o_dinv   = 0;                       // 400,000
  const size_t o_flag   = 400000;                  // 16 (flag, total)
  const size_t o_deg    = 400016;                  // 400,000
  const size_t o_rowptr = 800016;                  // 400,004 (NN+1)
  const size_t o_cursor = 1200032;                 // 400,000
  const size_t o_bsum   = 1600032;                 // 1,024 (<=256 ints)
  const size_t o_srcs   = 1601056;                 // 4*E = 6,400,000
  const size_t o_h      = 8001056;                 // 51,200,000
  const size_t o_out1   = 59201056;                // 51,200,000
  const size_t need_csr = 110401056;

  float* dinv   = (float*)(ws + o_dinv);
  int*   flag   = (int*)(ws + o_flag);
  int*   total  = flag + 1;
  int*   deg    = (int*)(ws + o_deg);
  int*   rowptr = (int*)(ws + o_rowptr);
  int*   cursor = (int*)(ws + o_cursor);
  int*   bsum   = (int*)(ws + o_bsum);
  int*   srcs   = (int*)(ws + o_srcs);
  float* h      = (float*)(ws + o_h);
  float* out1   = (float*)(ws + o_out1);

  k_detect<<<1, 64, 0, stream>>>(e, flag, E);
  k_zero_i32<<<(NN + 255) / 256, 256, 0, stream>>>(deg, NN);
  k_deg_count<<<(E + 255) / 256, 256, 0, stream>>>(e, flag, deg, E);
  k_dinv<<<(NN + 255) / 256, 256, 0, stream>>>(deg, dinv);

  if (ws_size >= need_csr) {
    // ---- CSR gather path ----
    const int nb = (NN + 1023) / 1024;  // 98
    k_scan_part<<<nb, 256, 0, stream>>>(deg, rowptr, bsum);
    k_scan_mid<<<1, 256, 0, stream>>>(bsum, nb, total);
    k_scan_add<<<(NN + 256) / 256, 256, 0, stream>>>(rowptr, bsum, total, cursor);
    k_fill<<<(E + 255) / 256, 256, 0, stream>>>(e, flag, cursor, srcs, E);

    k_gemm<128, false><<<(NN + 31) / 32, 256, 0, stream>>>(x, W1, h, NN);
    k_gather<128><<<(NN + 7) / 8, 256, 0, stream>>>(rowptr, srcs, dinv, h, b1, out1);

    k_gemm<64, true><<<(NN + 63) / 64, 256, 0, stream>>>(out1, W2, h, NN);
    k_gather<64><<<(NN + 15) / 16, 256, 0, stream>>>(rowptr, srcs, dinv, h, b2, out);
  } else {
    // ---- fallback: atomic scatter path (fits in ~103 MB) ----
    float* hF    = (float*)(ws + (1 << 20));
    float* out1F = (float*)(ws + (1 << 20) + 51200000);
    k_gemm<128, false><<<(NN + 31) / 32, 256, 0, stream>>>(x, W1, hF, NN);
    k_self_bias<128><<<(NN * 32 + 255) / 256, 256, 0, stream>>>(hF, dinv, b1, out1F);
    long long tot1 = (long long)E * 32;
    k_scatter<128><<<(int)((tot1 + 255) / 256), 256, 0, stream>>>(e, flag, dinv, hF, out1F, E);
    k_gemm<64, true><<<(NN + 63) / 64, 256, 0, stream>>>(out1F, W2, hF, NN);
    k_self_bias<64><<<(NN * 16 + 255) / 256, 256, 0, stream>>>(hF, dinv, b2, out);
    long long tot2 = (long long)E * 16;
    k_scatter<64><<<(int)((tot2 + 255) / 256), 256, 0, stream>>>(e, flag, dinv, hF, out, E);
  }
}

// Round 4
// 445.748 us; speedup vs baseline: 9.5292x; 1.2106x over previous
//
#include <hip/hip_runtime.h>
#include <hip/hip_fp16.h>

#define NN 100000

// ---------------- helpers ----------------
__device__ __forceinline__ void fma4(float4& a, float s, const float4& w) {
  a.x = fmaf(s, w.x, a.x);
  a.y = fmaf(s, w.y, a.y);
  a.z = fmaf(s, w.z, a.z);
  a.w = fmaf(s, w.w, a.w);
}

// accumulate 8 halves (as uint4) scaled by w into a[0..8)
__device__ __forceinline__ void acc8(float* a, float w, uint4 q) {
  const __half2* p = (const __half2*)&q;
#pragma unroll
  for (int j = 0; j < 4; ++j) {
    float2 f = __half22float2(p[j]);
    a[2 * j]     = fmaf(w, f.x, a[2 * j]);
    a[2 * j + 1] = fmaf(w, f.y, a[2 * j + 1]);
  }
}

__device__ __forceinline__ uint2 pack4h(float4 a) {
  __half2 lo = __floats2half2_rn(a.x, a.y);
  __half2 hi = __floats2half2_rn(a.z, a.w);
  uint2 r;
  r.x = *(const unsigned int*)&lo;
  r.y = *(const unsigned int*)&hi;
  return r;
}

// Detect whether edge_index is stored as int64 (little-endian: odd words all 0
// since values < 100000) or int32. flag=1 -> int64, flag=0 -> int32.
__global__ void k_detect(const int* __restrict__ e, int* flag, int E) {
  if (threadIdx.x == 0 && blockIdx.x == 0) {
    int n = E < 64 ? E : 64;
    int m = 1;
    for (int i = 0; i < n; ++i) {
      if (e[2 * i + 1] != 0) { m = 0; break; }
    }
    *flag = m;
  }
}

__global__ void k_zero_i32(int* p, int n) {
  int i = blockIdx.x * 256 + threadIdx.x;
  if (i < n) p[i] = 0;
}

__global__ void k_deg_count(const int* __restrict__ e, const int* __restrict__ flag,
                            int* __restrict__ deg, int E) {
  int i = blockIdx.x * 256 + threadIdx.x;
  if (i >= E) return;
  int m = *flag;
  int d = m ? e[2 * (E + i)] : e[E + i];
  atomicAdd(&deg[d], 1);
}

// dinv[i] = rsqrt(deg[i] + 1)   (+1 = self loop)
__global__ void k_dinv(const int* __restrict__ deg, float* __restrict__ dinv) {
  int i = blockIdx.x * 256 + threadIdx.x;
  if (i < NN) dinv[i] = rsqrtf((float)(deg[i] + 1));
}

// ---------------- hierarchical scan (3 kernels) ----------------
__global__ __launch_bounds__(256) void k_scan_part(const int* __restrict__ deg,
                                                   int* __restrict__ rowptr,
                                                   int* __restrict__ bsum) {
  __shared__ int s[256];
  const int tid = threadIdx.x;
  const int base = blockIdx.x * 1024 + tid * 4;
  int v0 = (base + 0 < NN) ? deg[base + 0] : 0;
  int v1 = (base + 1 < NN) ? deg[base + 1] : 0;
  int v2 = (base + 2 < NN) ? deg[base + 2] : 0;
  int v3 = (base + 3 < NN) ? deg[base + 3] : 0;
  int tsum = v0 + v1 + v2 + v3;
  s[tid] = tsum;
  __syncthreads();
#pragma unroll
  for (int off = 1; off < 256; off <<= 1) {
    int t = (tid >= off) ? s[tid - off] : 0;
    __syncthreads();
    s[tid] += t;
    __syncthreads();
  }
  int p = s[tid] - tsum;
  if (tid == 255) bsum[blockIdx.x] = s[255];
  if (base + 0 < NN) rowptr[base + 0] = p; p += v0;
  if (base + 1 < NN) rowptr[base + 1] = p; p += v1;
  if (base + 2 < NN) rowptr[base + 2] = p; p += v2;
  if (base + 3 < NN) rowptr[base + 3] = p;
}

__global__ __launch_bounds__(256) void k_scan_mid(int* __restrict__ bsum, int nb,
                                                  int* __restrict__ total) {
  __shared__ int s[256];
  const int tid = threadIdx.x;
  int v = (tid < nb) ? bsum[tid] : 0;
  s[tid] = v;
  __syncthreads();
#pragma unroll
  for (int off = 1; off < 256; off <<= 1) {
    int t = (tid >= off) ? s[tid - off] : 0;
    __syncthreads();
    s[tid] += t;
    __syncthreads();
  }
  if (tid < nb) bsum[tid] = s[tid] - v;
  if (tid == 255) *total = s[255];
}

__global__ void k_scan_add(int* __restrict__ rowptr, const int* __restrict__ bsum,
                           const int* __restrict__ total, int* __restrict__ cursor) {
  int i = blockIdx.x * 256 + threadIdx.x;
  if (i < NN) {
    int v = rowptr[i] + bsum[i >> 10];
    rowptr[i] = v;
    cursor[i] = v;
  } else if (i == NN) {
    rowptr[NN] = *total;
  }
}

// Bucket edges by dst: srcs[rowptr[d] ...] = list of srcs into d.
__global__ void k_fill(const int* __restrict__ e, const int* __restrict__ flag,
                       int* __restrict__ cursor, int* __restrict__ srcs, int E) {
  int i = blockIdx.x * 256 + threadIdx.x;
  if (i >= E) return;
  int m = *flag;
  int s, d;
  if (m) { s = e[2 * i]; d = e[2 * (E + i)]; }
  else   { s = e[i];     d = e[E + i]; }
  int p = atomicAdd(&cursor[d], 1);
  srcs[p] = s;
}

// Gather-reduce per node from fp16 h:
// out[d] = dinv[d]*(sum_{s in in(d)} dinv[s]*h[s] + dinv[d]*h[d]) + b
// C/8 lanes per node, 16B (8 halves) per lane.
template <int C>
__global__ __launch_bounds__(256) void k_gather_h(const int* __restrict__ rowptr,
                                                  const int* __restrict__ srcs,
                                                  const float* __restrict__ dinv,
                                                  const __half* __restrict__ h,
                                                  const float* __restrict__ b,
                                                  float* __restrict__ out) {
  constexpr int LPN = C / 8;      // lanes per node
  constexpr int NPW = 64 / LPN;   // nodes per wave
  constexpr int NPB = NPW * 4;    // nodes per block (4 waves)
  const int wave = threadIdx.x >> 6;
  const int lane = threadIdx.x & 63;
  const int grp = lane / LPN;
  const int li = lane % LPN;
  const int node = blockIdx.x * NPB + wave * NPW + grp;
  if (node >= NN) return;
  const float dd = dinv[node];
  float acc[8];
  {
    uint4 q = *(const uint4*)(h + (long long)node * C + li * 8);
    const __half2* p = (const __half2*)&q;
#pragma unroll
    for (int j = 0; j < 4; ++j) {
      float2 f = __half22float2(p[j]);
      acc[2 * j]     = dd * f.x;
      acc[2 * j + 1] = dd * f.y;
    }
  }
  const int beg = rowptr[node], end = rowptr[node + 1];
  int e = beg;
  for (; e + 2 <= end; e += 2) {
    int s0 = srcs[e], s1 = srcs[e + 1];
    float w0 = dinv[s0], w1 = dinv[s1];
    uint4 q0 = *(const uint4*)(h + (long long)s0 * C + li * 8);
    uint4 q1 = *(const uint4*)(h + (long long)s1 * C + li * 8);
    acc8(acc, w0, q0);
    acc8(acc, w1, q1);
  }
  if (e < end) {
    int s0 = srcs[e];
    float w0 = dinv[s0];
    uint4 q0 = *(const uint4*)(h + (long long)s0 * C + li * 8);
    acc8(acc, w0, q0);
  }
  const float4* b4 = (const float4*)b;
  float4 bb0 = b4[li * 2], bb1 = b4[li * 2 + 1];
  float4 o0, o1;
  o0.x = fmaf(dd, acc[0], bb0.x);
  o0.y = fmaf(dd, acc[1], bb0.y);
  o0.z = fmaf(dd, acc[2], bb0.z);
  o0.w = fmaf(dd, acc[3], bb0.w);
  o1.x = fmaf(dd, acc[4], bb1.x);
  o1.y = fmaf(dd, acc[5], bb1.y);
  o1.z = fmaf(dd, acc[6], bb1.z);
  o1.w = fmaf(dd, acc[7], bb1.w);
  float4* op = (float4*)(out + (long long)node * C + li * 8);
  op[0] = o0;
  op[1] = o1;
}

// C[M,N] = A[M,128] @ W[128,N]; optional ReLU on A load; fp32 or fp16 output.
template <int N, bool RELU, bool HOUT>
__global__ __launch_bounds__(256) void k_gemm(const float* __restrict__ A,
                                              const float* __restrict__ W,
                                              void* __restrict__ outv, int M) {
  constexpr int K4 = 32;
  constexpr int N4 = N / 4;
  constexpr int CG = N4;
  constexpr int RQ = 256 / CG;
  constexpr int ROWS = RQ * 4;
  __shared__ float4 Wl[128 * N4];
  __shared__ float4 Xl[ROWS * K4];
  const int tid = threadIdx.x;
  const float4* W4 = (const float4*)W;
  for (int i = tid; i < 128 * N4; i += 256) Wl[i] = W4[i];
  const long long row0 = (long long)blockIdx.x * ROWS;
  const float4* A4 = (const float4*)A;
  for (int i = tid; i < ROWS * K4; i += 256) {
    int r = i >> 5;
    long long row = row0 + r;
    float4 v = make_float4(0.f, 0.f, 0.f, 0.f);
    if (row < M) v = A4[row * K4 + (i & 31)];
    if (RELU) {
      v.x = fmaxf(v.x, 0.f); v.y = fmaxf(v.y, 0.f);
      v.z = fmaxf(v.z, 0.f); v.w = fmaxf(v.w, 0.f);
    }
    Xl[i] = v;
  }
  __syncthreads();
  const int c = tid % CG;
  const int rb = (tid / CG) * 4;
  float4 a0 = make_float4(0, 0, 0, 0), a1 = a0, a2 = a0, a3 = a0;
#pragma unroll 4
  for (int k4 = 0; k4 < K4; ++k4) {
    float4 w0 = Wl[(k4 * 4 + 0) * N4 + c];
    float4 w1 = Wl[(k4 * 4 + 1) * N4 + c];
    float4 w2 = Wl[(k4 * 4 + 2) * N4 + c];
    float4 w3 = Wl[(k4 * 4 + 3) * N4 + c];
    float4 x0 = Xl[(rb + 0) * K4 + k4];
    float4 x1 = Xl[(rb + 1) * K4 + k4];
    float4 x2 = Xl[(rb + 2) * K4 + k4];
    float4 x3 = Xl[(rb + 3) * K4 + k4];
    fma4(a0, x0.x, w0); fma4(a0, x0.y, w1); fma4(a0, x0.z, w2); fma4(a0, x0.w, w3);
    fma4(a1, x1.x, w0); fma4(a1, x1.y, w1); fma4(a1, x1.z, w2); fma4(a1, x1.w, w3);
    fma4(a2, x2.x, w0); fma4(a2, x2.y, w1); fma4(a2, x2.z, w2); fma4(a2, x2.w, w3);
    fma4(a3, x3.x, w0); fma4(a3, x3.y, w1); fma4(a3, x3.z, w2); fma4(a3, x3.w, w3);
  }
  long long row = row0 + rb;
  if (HOUT) {
    __half* O = (__half*)outv;
    if (row + 0 < M) *(uint2*)(O + (row + 0) * N + c * 4) = pack4h(a0);
    if (row + 1 < M) *(uint2*)(O + (row + 1) * N + c * 4) = pack4h(a1);
    if (row + 2 < M) *(uint2*)(O + (row + 2) * N + c * 4) = pack4h(a2);
    if (row + 3 < M) *(uint2*)(O + (row + 3) * N + c * 4) = pack4h(a3);
  } else {
    float4* O4 = (float4*)outv;
    if (row + 0 < M) O4[(row + 0) * N4 + c] = a0;
    if (row + 1 < M) O4[(row + 1) * N4 + c] = a1;
    if (row + 2 < M) O4[(row + 2) * N4 + c] = a2;
    if (row + 3 < M) O4[(row + 3) * N4 + c] = a3;
  }
}

// ---------------- fallback (atomic scatter) kernels ----------------
template <int C>
__global__ void k_self_bias(const float* __restrict__ h, const float* __restrict__ dinv,
                            const float* __restrict__ b, float* __restrict__ out) {
  constexpr int C4 = C / 4;
  int gid = blockIdx.x * 256 + threadIdx.x;
  if (gid >= NN * C4) return;
  int node = gid / C4;
  int cq = gid % C4;
  float di = dinv[node];
  float sc = di * di;
  float4 v = ((const float4*)h)[gid];
  float4 bb = ((const float4*)b)[cq];
  float4 o;
  o.x = fmaf(v.x, sc, bb.x);
  o.y = fmaf(v.y, sc, bb.y);
  o.z = fmaf(v.z, sc, bb.z);
  o.w = fmaf(v.w, sc, bb.w);
  ((float4*)out)[gid] = o;
}

template <int C>
__global__ void k_scatter(const int* __restrict__ e, const int* __restrict__ flag,
                          const float* __restrict__ dinv, const float* __restrict__ h,
                          float* __restrict__ out, int E) {
  constexpr int TPE = C / 4;
  long long gid = (long long)blockIdx.x * blockDim.x + threadIdx.x;
  int ei = (int)(gid / TPE);
  int cq = (int)(gid % TPE);
  if (ei >= E) return;
  int m = *flag;
  int s, d;
  if (m) { s = e[2 * ei]; d = e[2 * (E + ei)]; }
  else   { s = e[ei];     d = e[E + ei]; }
  float nrm = dinv[s] * dinv[d];
  float4 v = ((const float4*)h)[(long long)s * TPE + cq];
  float* op = out + (long long)d * C + (long long)cq * 4;
  unsafeAtomicAdd(op + 0, v.x * nrm);
  unsafeAtomicAdd(op + 1, v.y * nrm);
  unsafeAtomicAdd(op + 2, v.z * nrm);
  unsafeAtomicAdd(op + 3, v.w * nrm);
}

extern "C" void kernel_launch(void* const* d_in, const int* in_sizes, int n_in,
                              void* d_out, int out_size, void* d_ws, size_t ws_size,
                              hipStream_t stream) {
  const float* x  = (const float*)d_in[0];
  const int*   e  = (const int*)d_in[1];
  const float* W1 = (const float*)d_in[2];
  const float* b1 = (const float*)d_in[3];
  const float* W2 = (const float*)d_in[4];
  const float* b2 = (const float*)d_in[5];
  float* out = (float*)d_out;
  const int E = in_sizes[1] / 2;

  char* ws = (char*)d_ws;
  const size_t o_dinv   = 0;                       // 400,000
  const size_t o_flag   = 400000;                  // 16 (flag, total)
  const size_t o_deg    = 400016;                  // 400,000
  const size_t o_rowptr = 800016;                  // 400,004 (NN+1)
  const size_t o_cursor = 1200032;                 // 400,000
  const size_t o_bsum   = 1600032;                 // 1,024
  const size_t o_srcs   = 1601056;                 // 4*E = 6,400,000
  const size_t o_h      = 8001056;                 // fp16 h: 25.6 MB max
  const size_t o_out1   = 59201056;                // fp32 out1: 51.2 MB
  const size_t need_csr = 110401056;

  float* dinv   = (float*)(ws + o_dinv);
  int*   flag   = (int*)(ws + o_flag);
  int*   total  = flag + 1;
  int*   deg    = (int*)(ws + o_deg);
  int*   rowptr = (int*)(ws + o_rowptr);
  int*   cursor = (int*)(ws + o_cursor);
  int*   bsum   = (int*)(ws + o_bsum);
  int*   srcs   = (int*)(ws + o_srcs);
  __half* hh    = (__half*)(ws + o_h);
  float* out1   = (float*)(ws + o_out1);

  k_detect<<<1, 64, 0, stream>>>(e, flag, E);
  k_zero_i32<<<(NN + 255) / 256, 256, 0, stream>>>(deg, NN);
  k_deg_count<<<(E + 255) / 256, 256, 0, stream>>>(e, flag, deg, E);
  k_dinv<<<(NN + 255) / 256, 256, 0, stream>>>(deg, dinv);

  if (ws_size >= need_csr) {
    // ---- CSR gather path, fp16 messages ----
    const int nb = (NN + 1023) / 1024;  // 98
    k_scan_part<<<nb, 256, 0, stream>>>(deg, rowptr, bsum);
    k_scan_mid<<<1, 256, 0, stream>>>(bsum, nb, total);
    k_scan_add<<<(NN + 256) / 256, 256, 0, stream>>>(rowptr, bsum, total, cursor);
    k_fill<<<(E + 255) / 256, 256, 0, stream>>>(e, flag, cursor, srcs, E);

    k_gemm<128, false, true><<<(NN + 31) / 32, 256, 0, stream>>>(x, W1, hh, NN);
    k_gather_h<128><<<(NN + 15) / 16, 256, 0, stream>>>(rowptr, srcs, dinv, hh, b1, out1);

    k_gemm<64, true, true><<<(NN + 63) / 64, 256, 0, stream>>>(out1, W2, hh, NN);
    k_gather_h<64><<<(NN + 31) / 32, 256, 0, stream>>>(rowptr, srcs, dinv, hh, b2, out);
  } else {
    // ---- fallback: fp32 atomic scatter path ----
    float* hF    = (float*)(ws + (1 << 20));
    float* out1F = (float*)(ws + (1 << 20) + 51200000);
    k_gemm<128, false, false><<<(NN + 31) / 32, 256, 0, stream>>>(x, W1, hF, NN);
    k_self_bias<128><<<(NN * 32 + 255) / 256, 256, 0, stream>>>(hF, dinv, b1, out1F);
    long long tot1 = (long long)E * 32;
    k_scatter<128><<<(int)((tot1 + 255) / 256), 256, 0, stream>>>(e, flag, dinv, hF, out1F, E);
    k_gemm<64, true, false><<<(NN + 63) / 64, 256, 0, stream>>>(out1F, W2, hF, NN);
    k_self_bias<64><<<(NN * 16 + 255) / 256, 256, 0, stream>>>(hF, dinv, b2, out);
    long long tot2 = (long long)E * 16;
    k_scatter<64><<<(int)((tot2 + 255) / 256), 256, 0, stream>>>(e, flag, dinv, hF, out, E);
  }
}

// Round 5
// 369.696 us; speedup vs baseline: 11.4895x; 1.2057x over previous
//
#include <hip/hip_runtime.h>
#include <hip/hip_fp16.h>

#define NN 100000
#define NBKT 196  // ceil(NN / 512)

// ---------------- helpers ----------------
__device__ __forceinline__ void fma4(float4& a, float s, const float4& w) {
  a.x = fmaf(s, w.x, a.x);
  a.y = fmaf(s, w.y, a.y);
  a.z = fmaf(s, w.z, a.z);
  a.w = fmaf(s, w.w, a.w);
}

// accumulate 8 halves (as uint4) scaled by w into a[0..8)
__device__ __forceinline__ void acc8(float* a, float w, uint4 q) {
  const __half2* p = (const __half2*)&q;
#pragma unroll
  for (int j = 0; j < 4; ++j) {
    float2 f = __half22float2(p[j]);
    a[2 * j]     = fmaf(w, f.x, a[2 * j]);
    a[2 * j + 1] = fmaf(w, f.y, a[2 * j + 1]);
  }
}

__device__ __forceinline__ uint2 pack4h(float4 a) {
  __half2 lo = __floats2half2_rn(a.x, a.y);
  __half2 hi = __floats2half2_rn(a.z, a.w);
  uint2 r;
  r.x = *(const unsigned int*)&lo;
  r.y = *(const unsigned int*)&hi;
  return r;
}

// Detect whether edge_index is stored as int64 (little-endian: odd words all 0
// since values < 100000) or int32. flag=1 -> int64, flag=0 -> int32.
__global__ void k_detect(const int* __restrict__ e, int* flag, int E) {
  if (threadIdx.x == 0 && blockIdx.x == 0) {
    int n = E < 64 ? E : 64;
    int m = 1;
    for (int i = 0; i < n; ++i) {
      if (e[2 * i + 1] != 0) { m = 0; break; }
    }
    *flag = m;
  }
}

__global__ void k_zero_i32(int* p, int n) {
  int i = blockIdx.x * 256 + threadIdx.x;
  if (i < n) p[i] = 0;
}

__global__ void k_deg_count(const int* __restrict__ e, const int* __restrict__ flag,
                            int* __restrict__ deg, int E) {
  int i = blockIdx.x * 256 + threadIdx.x;
  if (i >= E) return;
  int m = *flag;
  int d = m ? e[2 * (E + i)] : e[E + i];
  atomicAdd(&deg[d], 1);
}

// dinv[i] = rsqrt(deg[i] + 1)   (+1 = self loop)
__global__ void k_dinv(const int* __restrict__ deg, float* __restrict__ dinv) {
  int i = blockIdx.x * 256 + threadIdx.x;
  if (i < NN) dinv[i] = rsqrtf((float)(deg[i] + 1));
}

// ---------------- hierarchical scan (3 kernels) ----------------
__global__ __launch_bounds__(256) void k_scan_part(const int* __restrict__ deg,
                                                   int* __restrict__ rowptr,
                                                   int* __restrict__ bsum) {
  __shared__ int s[256];
  const int tid = threadIdx.x;
  const int base = blockIdx.x * 1024 + tid * 4;
  int v0 = (base + 0 < NN) ? deg[base + 0] : 0;
  int v1 = (base + 1 < NN) ? deg[base + 1] : 0;
  int v2 = (base + 2 < NN) ? deg[base + 2] : 0;
  int v3 = (base + 3 < NN) ? deg[base + 3] : 0;
  int tsum = v0 + v1 + v2 + v3;
  s[tid] = tsum;
  __syncthreads();
#pragma unroll
  for (int off = 1; off < 256; off <<= 1) {
    int t = (tid >= off) ? s[tid - off] : 0;
    __syncthreads();
    s[tid] += t;
    __syncthreads();
  }
  int p = s[tid] - tsum;
  if (tid == 255) bsum[blockIdx.x] = s[255];
  if (base + 0 < NN) rowptr[base + 0] = p; p += v0;
  if (base + 1 < NN) rowptr[base + 1] = p; p += v1;
  if (base + 2 < NN) rowptr[base + 2] = p; p += v2;
  if (base + 3 < NN) rowptr[base + 3] = p;
}

__global__ __launch_bounds__(256) void k_scan_mid(int* __restrict__ bsum, int nb,
                                                  int* __restrict__ total) {
  __shared__ int s[256];
  const int tid = threadIdx.x;
  int v = (tid < nb) ? bsum[tid] : 0;
  s[tid] = v;
  __syncthreads();
#pragma unroll
  for (int off = 1; off < 256; off <<= 1) {
    int t = (tid >= off) ? s[tid - off] : 0;
    __syncthreads();
    s[tid] += t;
    __syncthreads();
  }
  if (tid < nb) bsum[tid] = s[tid] - v;
  if (tid == 255) *total = s[255];
}

__global__ void k_scan_add(int* __restrict__ rowptr, const int* __restrict__ bsum,
                           const int* __restrict__ total) {
  int i = blockIdx.x * 256 + threadIdx.x;
  if (i < NN) {
    rowptr[i] = rowptr[i] + bsum[i >> 10];
  } else if (i == NN) {
    rowptr[NN] = *total;
  }
}

// gcur[b] = rowptr[512*b]  (bucket write cursors for binA)
__global__ void k_gcur_init(const int* __restrict__ rowptr, int* __restrict__ gcur) {
  int b = blockIdx.x * 256 + threadIdx.x;
  if (b < NBKT) gcur[b] = rowptr[b << 9];
}

// Stage A: bin edges into 196 dst-buckets (512 nodes each). Each block
// reserves a contiguous private range per bucket, so its writes to tmp are
// sequential within block-owned regions (no cross-XCD line bouncing).
__global__ __launch_bounds__(256) void k_binA(const int* __restrict__ e,
                                              const int* __restrict__ flag,
                                              int* __restrict__ gcur,
                                              unsigned int* __restrict__ tmp, int E) {
  __shared__ int cnt[256];   // per-bucket count, then reused via pcur
  __shared__ int pcur[256];  // per-bucket write cursor (global positions)
  const int tid = threadIdx.x;
  const int start = blockIdx.x * 4096;
  const int m = *flag;
  cnt[tid] = 0;
  __syncthreads();
  int ss[16], dd[16];
#pragma unroll
  for (int k = 0; k < 16; ++k) {
    int i = start + tid + k * 256;
    int s = -1, d = 0;
    if (i < E) {
      if (m) { s = e[2 * i]; d = e[2 * (E + i)]; }
      else   { s = e[i];     d = e[E + i]; }
      atomicAdd(&cnt[d >> 9], 1);
    }
    ss[k] = s; dd[k] = d;
  }
  __syncthreads();
  if (tid < NBKT && cnt[tid] > 0) pcur[tid] = atomicAdd(&gcur[tid], cnt[tid]);
  __syncthreads();
#pragma unroll
  for (int k = 0; k < 16; ++k) {
    if (ss[k] >= 0) {
      int b = dd[k] >> 9;
      int p = atomicAdd(&pcur[b], 1);
      tmp[p] = ((unsigned)ss[k] << 9) | (unsigned)(dd[k] & 511);
    }
  }
}

// Stage B: one block per bucket; scatter within the bucket's small contiguous
// srcs window (single-block-owned, L2-resident).
__global__ __launch_bounds__(256) void k_binB(const unsigned int* __restrict__ tmp,
                                              const int* __restrict__ rowptr,
                                              int* __restrict__ srcs) {
  __shared__ int lcur[512];
  const int tid = threadIdx.x;
  const int nb0 = blockIdx.x << 9;
  for (int i = tid; i < 512; i += 256) {
    int node = nb0 + i;
    lcur[i] = (node < NN) ? rowptr[node] : 0;
  }
  int endNode = nb0 + 512;
  if (endNode > NN) endNode = NN;
  const int beg = rowptr[nb0];
  const int end = rowptr[endNode];
  __syncthreads();
  for (int j = beg + tid; j < end; j += 256) {
    unsigned v = tmp[j];
    int p = atomicAdd(&lcur[v & 511], 1);
    srcs[p] = (int)(v >> 9);
  }
}

// Gather-reduce per node from fp16 h:
// out[d] = dinv[d]*(sum_{s in in(d)} dinv[s]*h[s] + dinv[d]*h[d]) + b
template <int C>
__global__ __launch_bounds__(256) void k_gather_h(const int* __restrict__ rowptr,
                                                  const int* __restrict__ srcs,
                                                  const float* __restrict__ dinv,
                                                  const __half* __restrict__ h,
                                                  const float* __restrict__ b,
                                                  float* __restrict__ out) {
  constexpr int LPN = C / 8;      // lanes per node
  constexpr int NPW = 64 / LPN;   // nodes per wave
  constexpr int NPB = NPW * 4;    // nodes per block (4 waves)
  const int wave = threadIdx.x >> 6;
  const int lane = threadIdx.x & 63;
  const int grp = lane / LPN;
  const int li = lane % LPN;
  const int node = blockIdx.x * NPB + wave * NPW + grp;
  if (node >= NN) return;
  const float dd = dinv[node];
  float acc[8];
  {
    uint4 q = *(const uint4*)(h + (long long)node * C + li * 8);
    const __half2* p = (const __half2*)&q;
#pragma unroll
    for (int j = 0; j < 4; ++j) {
      float2 f = __half22float2(p[j]);
      acc[2 * j]     = dd * f.x;
      acc[2 * j + 1] = dd * f.y;
    }
  }
  const int beg = rowptr[node], end = rowptr[node + 1];
  int e = beg;
  for (; e + 2 <= end; e += 2) {
    int s0 = srcs[e], s1 = srcs[e + 1];
    float w0 = dinv[s0], w1 = dinv[s1];
    uint4 q0 = *(const uint4*)(h + (long long)s0 * C + li * 8);
    uint4 q1 = *(const uint4*)(h + (long long)s1 * C + li * 8);
    acc8(acc, w0, q0);
    acc8(acc, w1, q1);
  }
  if (e < end) {
    int s0 = srcs[e];
    float w0 = dinv[s0];
    uint4 q0 = *(const uint4*)(h + (long long)s0 * C + li * 8);
    acc8(acc, w0, q0);
  }
  const float4* b4 = (const float4*)b;
  float4 bb0 = b4[li * 2], bb1 = b4[li * 2 + 1];
  float4 o0, o1;
  o0.x = fmaf(dd, acc[0], bb0.x);
  o0.y = fmaf(dd, acc[1], bb0.y);
  o0.z = fmaf(dd, acc[2], bb0.z);
  o0.w = fmaf(dd, acc[3], bb0.w);
  o1.x = fmaf(dd, acc[4], bb1.x);
  o1.y = fmaf(dd, acc[5], bb1.y);
  o1.z = fmaf(dd, acc[6], bb1.z);
  o1.w = fmaf(dd, acc[7], bb1.w);
  float4* op = (float4*)(out + (long long)node * C + li * 8);
  op[0] = o0;
  op[1] = o1;
}

// C[M,N] = A[M,128] @ W[128,N]; optional ReLU on A load; fp32 or fp16 output.
template <int N, bool RELU, bool HOUT>
__global__ __launch_bounds__(256) void k_gemm(const float* __restrict__ A,
                                              const float* __restrict__ W,
                                              void* __restrict__ outv, int M) {
  constexpr int K4 = 32;
  constexpr int N4 = N / 4;
  constexpr int CG = N4;
  constexpr int RQ = 256 / CG;
  constexpr int ROWS = RQ * 4;
  __shared__ float4 Wl[128 * N4];
  __shared__ float4 Xl[ROWS * K4];
  const int tid = threadIdx.x;
  const float4* W4 = (const float4*)W;
  for (int i = tid; i < 128 * N4; i += 256) Wl[i] = W4[i];
  const long long row0 = (long long)blockIdx.x * ROWS;
  const float4* A4 = (const float4*)A;
  for (int i = tid; i < ROWS * K4; i += 256) {
    int r = i >> 5;
    long long row = row0 + r;
    float4 v = make_float4(0.f, 0.f, 0.f, 0.f);
    if (row < M) v = A4[row * K4 + (i & 31)];
    if (RELU) {
      v.x = fmaxf(v.x, 0.f); v.y = fmaxf(v.y, 0.f);
      v.z = fmaxf(v.z, 0.f); v.w = fmaxf(v.w, 0.f);
    }
    Xl[i] = v;
  }
  __syncthreads();
  const int c = tid % CG;
  const int rb = (tid / CG) * 4;
  float4 a0 = make_float4(0, 0, 0, 0), a1 = a0, a2 = a0, a3 = a0;
#pragma unroll 4
  for (int k4 = 0; k4 < K4; ++k4) {
    float4 w0 = Wl[(k4 * 4 + 0) * N4 + c];
    float4 w1 = Wl[(k4 * 4 + 1) * N4 + c];
    float4 w2 = Wl[(k4 * 4 + 2) * N4 + c];
    float4 w3 = Wl[(k4 * 4 + 3) * N4 + c];
    float4 x0 = Xl[(rb + 0) * K4 + k4];
    float4 x1 = Xl[(rb + 1) * K4 + k4];
    float4 x2 = Xl[(rb + 2) * K4 + k4];
    float4 x3 = Xl[(rb + 3) * K4 + k4];
    fma4(a0, x0.x, w0); fma4(a0, x0.y, w1); fma4(a0, x0.z, w2); fma4(a0, x0.w, w3);
    fma4(a1, x1.x, w0); fma4(a1, x1.y, w1); fma4(a1, x1.z, w2); fma4(a1, x1.w, w3);
    fma4(a2, x2.x, w0); fma4(a2, x2.y, w1); fma4(a2, x2.z, w2); fma4(a2, x2.w, w3);
    fma4(a3, x3.x, w0); fma4(a3, x3.y, w1); fma4(a3, x3.z, w2); fma4(a3, x3.w, w3);
  }
  long long row = row0 + rb;
  if (HOUT) {
    __half* O = (__half*)outv;
    if (row + 0 < M) *(uint2*)(O + (row + 0) * N + c * 4) = pack4h(a0);
    if (row + 1 < M) *(uint2*)(O + (row + 1) * N + c * 4) = pack4h(a1);
    if (row + 2 < M) *(uint2*)(O + (row + 2) * N + c * 4) = pack4h(a2);
    if (row + 3 < M) *(uint2*)(O + (row + 3) * N + c * 4) = pack4h(a3);
  } else {
    float4* O4 = (float4*)outv;
    if (row + 0 < M) O4[(row + 0) * N4 + c] = a0;
    if (row + 1 < M) O4[(row + 1) * N4 + c] = a1;
    if (row + 2 < M) O4[(row + 2) * N4 + c] = a2;
    if (row + 3 < M) O4[(row + 3) * N4 + c] = a3;
  }
}

// ---------------- fallback (atomic scatter) kernels ----------------
template <int C>
__global__ void k_self_bias(const float* __restrict__ h, const float* __restrict__ dinv,
                            const float* __restrict__ b, float* __restrict__ out) {
  constexpr int C4 = C / 4;
  int gid = blockIdx.x * 256 + threadIdx.x;
  if (gid >= NN * C4) return;
  int node = gid / C4;
  int cq = gid % C4;
  float di = dinv[node];
  float sc = di * di;
  float4 v = ((const float4*)h)[gid];
  float4 bb = ((const float4*)b)[cq];
  float4 o;
  o.x = fmaf(v.x, sc, bb.x);
  o.y = fmaf(v.y, sc, bb.y);
  o.z = fmaf(v.z, sc, bb.z);
  o.w = fmaf(v.w, sc, bb.w);
  ((float4*)out)[gid] = o;
}

template <int C>
__global__ void k_scatter(const int* __restrict__ e, const int* __restrict__ flag,
                          const float* __restrict__ dinv, const float* __restrict__ h,
                          float* __restrict__ out, int E) {
  constexpr int TPE = C / 4;
  long long gid = (long long)blockIdx.x * blockDim.x + threadIdx.x;
  int ei = (int)(gid / TPE);
  int cq = (int)(gid % TPE);
  if (ei >= E) return;
  int m = *flag;
  int s, d;
  if (m) { s = e[2 * ei]; d = e[2 * (E + ei)]; }
  else   { s = e[ei];     d = e[E + ei]; }
  float nrm = dinv[s] * dinv[d];
  float4 v = ((const float4*)h)[(long long)s * TPE + cq];
  float* op = out + (long long)d * C + (long long)cq * 4;
  unsafeAtomicAdd(op + 0, v.x * nrm);
  unsafeAtomicAdd(op + 1, v.y * nrm);
  unsafeAtomicAdd(op + 2, v.z * nrm);
  unsafeAtomicAdd(op + 3, v.w * nrm);
}

extern "C" void kernel_launch(void* const* d_in, const int* in_sizes, int n_in,
                              void* d_out, int out_size, void* d_ws, size_t ws_size,
                              hipStream_t stream) {
  const float* x  = (const float*)d_in[0];
  const int*   e  = (const int*)d_in[1];
  const float* W1 = (const float*)d_in[2];
  const float* b1 = (const float*)d_in[3];
  const float* W2 = (const float*)d_in[4];
  const float* b2 = (const float*)d_in[5];
  float* out = (float*)d_out;
  const int E = in_sizes[1] / 2;

  char* ws = (char*)d_ws;
  const size_t o_dinv   = 0;          // 400,000
  const size_t o_flag   = 400000;     // 16 (flag, total)
  const size_t o_deg    = 400016;     // 400,000
  const size_t o_rowptr = 800016;     // 400,004 (NN+1)
  const size_t o_bsum   = 1200032;    // 1,024
  const size_t o_gcur   = 1201056;    // 784 (NBKT ints)
  const size_t o_tmp    = 1201856;    // 4*E = 6,400,000
  const size_t o_srcs   = 7601856;    // 4*E = 6,400,000
  const size_t o_h      = 14001856;   // fp16 h: 25.6 MB max
  const size_t o_out1   = 39601856;   // fp32 out1: 51.2 MB
  const size_t need_csr = 90801856;

  float* dinv   = (float*)(ws + o_dinv);
  int*   flag   = (int*)(ws + o_flag);
  int*   total  = flag + 1;
  int*   deg    = (int*)(ws + o_deg);
  int*   rowptr = (int*)(ws + o_rowptr);
  int*   bsum   = (int*)(ws + o_bsum);
  int*   gcur   = (int*)(ws + o_gcur);
  unsigned int* tmp = (unsigned int*)(ws + o_tmp);
  int*   srcs   = (int*)(ws + o_srcs);
  __half* hh    = (__half*)(ws + o_h);
  float* out1   = (float*)(ws + o_out1);

  k_detect<<<1, 64, 0, stream>>>(e, flag, E);
  k_zero_i32<<<(NN + 255) / 256, 256, 0, stream>>>(deg, NN);
  k_deg_count<<<(E + 255) / 256, 256, 0, stream>>>(e, flag, deg, E);
  k_dinv<<<(NN + 255) / 256, 256, 0, stream>>>(deg, dinv);

  if (ws_size >= need_csr) {
    // ---- CSR gather path, fp16 messages, binned CSR build ----
    const int nb = (NN + 1023) / 1024;  // 98
    k_scan_part<<<nb, 256, 0, stream>>>(deg, rowptr, bsum);
    k_scan_mid<<<1, 256, 0, stream>>>(bsum, nb, total);
    k_scan_add<<<(NN + 256) / 256, 256, 0, stream>>>(rowptr, bsum, total);
    k_gcur_init<<<1, 256, 0, stream>>>(rowptr, gcur);
    k_binA<<<(E + 4095) / 4096, 256, 0, stream>>>(e, flag, gcur, tmp, E);
    k_binB<<<NBKT, 256, 0, stream>>>(tmp, rowptr, srcs);

    k_gemm<128, false, true><<<(NN + 31) / 32, 256, 0, stream>>>(x, W1, hh, NN);
    k_gather_h<128><<<(NN + 15) / 16, 256, 0, stream>>>(rowptr, srcs, dinv, hh, b1, out1);

    k_gemm<64, true, true><<<(NN + 63) / 64, 256, 0, stream>>>(out1, W2, hh, NN);
    k_gather_h<64><<<(NN + 31) / 32, 256, 0, stream>>>(rowptr, srcs, dinv, hh, b2, out);
  } else {
    // ---- fallback: fp32 atomic scatter path ----
    float* hF    = (float*)(ws + (1 << 20));
    float* out1F = (float*)(ws + (1 << 20) + 51200000);
    k_gemm<128, false, false><<<(NN + 31) / 32, 256, 0, stream>>>(x, W1, hF, NN);
    k_self_bias<128><<<(NN * 32 + 255) / 256, 256, 0, stream>>>(hF, dinv, b1, out1F);
    long long tot1 = (long long)E * 32;
    k_scatter<128><<<(int)((tot1 + 255) / 256), 256, 0, stream>>>(e, flag, dinv, hF, out1F, E);
    k_gemm<64, true, false><<<(NN + 63) / 64, 256, 0, stream>>>(out1F, W2, hF, NN);
    k_self_bias<64><<<(NN * 16 + 255) / 256, 256, 0, stream>>>(hF, dinv, b2, out);
    long long tot2 = (long long)E * 16;
    k_scatter<64><<<(int)((tot2 + 255) / 256), 256, 0, stream>>>(e, flag, dinv, hF, out, E);
  }
}

// Round 6
// 234.508 us; speedup vs baseline: 18.1129x; 1.5765x over previous
//
#include <hip/hip_runtime.h>
#include <hip/hip_fp16.h>

#define NN 100000
#define NBKT 196   // ceil(NN/512)
#define BCAP 16384 // slack-allocated tmp entries per bucket (mean 8192, sigma~90)

using f16x8 = __attribute__((ext_vector_type(8))) _Float16;
using f32x4 = __attribute__((ext_vector_type(4))) float;

// ---------------- helpers ----------------
__device__ __forceinline__ void fma4(float4& a, float s, const float4& w) {
  a.x = fmaf(s, w.x, a.x);
  a.y = fmaf(s, w.y, a.y);
  a.z = fmaf(s, w.z, a.z);
  a.w = fmaf(s, w.w, a.w);
}

// accumulate 8 halves (as uint4) scaled by w into a[0..8)
__device__ __forceinline__ void acc8(float* a, float w, uint4 q) {
  const __half2* p = (const __half2*)&q;
#pragma unroll
  for (int j = 0; j < 4; ++j) {
    float2 f = __half22float2(p[j]);
    a[2 * j]     = fmaf(w, f.x, a[2 * j]);
    a[2 * j + 1] = fmaf(w, f.y, a[2 * j + 1]);
  }
}

__device__ __forceinline__ unsigned packh2(float x, float y) {
  __half2 h = __floats2half2_rn(x, y);
  return *(unsigned*)&h;
}

// Detect int64 vs int32 edge_index layout.
__global__ void k_detect(const int* __restrict__ e, int* flag, int E) {
  if (threadIdx.x == 0 && blockIdx.x == 0) {
    int n = E < 64 ? E : 64;
    int m = 1;
    for (int i = 0; i < n; ++i) {
      if (e[2 * i + 1] != 0) { m = 0; break; }
    }
    *flag = m;
  }
}

__global__ void k_gcur_init(int* __restrict__ gcur) {
  int b = blockIdx.x * 256 + threadIdx.x;
  if (b < NBKT) gcur[b] = b * BCAP;
}

// Stage A: bin edges into NBKT dst-buckets (512 nodes each) with slack regions.
__global__ __launch_bounds__(256) void k_binA(const int* __restrict__ e,
                                              const int* __restrict__ flag,
                                              int* __restrict__ gcur,
                                              unsigned int* __restrict__ tmp, int E) {
  __shared__ int cnt[256];
  __shared__ int pcur[256];
  const int tid = threadIdx.x;
  const int start = blockIdx.x * 4096;
  const int m = *flag;
  cnt[tid] = 0;
  __syncthreads();
  int ss[16], dd[16];
#pragma unroll
  for (int k = 0; k < 16; ++k) {
    int i = start + tid + k * 256;
    int s = -1, d = 0;
    if (i < E) {
      if (m) { s = e[2 * i]; d = e[2 * (E + i)]; }
      else   { s = e[i];     d = e[E + i]; }
      atomicAdd(&cnt[d >> 9], 1);
    }
    ss[k] = s; dd[k] = d;
  }
  __syncthreads();
  if (tid < NBKT && cnt[tid] > 0) pcur[tid] = atomicAdd(&gcur[tid], cnt[tid]);
  __syncthreads();
#pragma unroll
  for (int k = 0; k < 16; ++k) {
    if (ss[k] >= 0) {
      int b = dd[k] >> 9;
      int p = atomicAdd(&pcur[b], 1);
      tmp[p] = ((unsigned)ss[k] << 9) | (unsigned)(dd[k] & 511);
    }
  }
}

// Exclusive scan of per-bucket totals (196 values) -> bktbase; rowptr[NN]=total.
__global__ __launch_bounds__(256) void k_bkt_scan(const int* __restrict__ gcur,
                                                  int* __restrict__ bktbase,
                                                  int* __restrict__ rowptr) {
  __shared__ int s[256];
  const int tid = threadIdx.x;
  int v = (tid < NBKT) ? (gcur[tid] - tid * BCAP) : 0;
  s[tid] = v;
  __syncthreads();
#pragma unroll
  for (int off = 1; off < 256; off <<= 1) {
    int t = (tid >= off) ? s[tid - off] : 0;
    __syncthreads();
    s[tid] += t;
    __syncthreads();
  }
  if (tid < NBKT) bktbase[tid] = s[tid] - v;
  if (tid == 255) {
    bktbase[NBKT] = s[255];
    rowptr[NN] = s[255];
  }
}

// Stage B: per bucket: LDS histogram (= deg) -> dinv + rowptr, local scan,
// then place srcs into the bucket's contiguous window.
__global__ __launch_bounds__(256) void k_binB(const unsigned int* __restrict__ tmp,
                                              const int* __restrict__ gcur,
                                              const int* __restrict__ bktbase,
                                              int* __restrict__ rowptr,
                                              float* __restrict__ dinv,
                                              int* __restrict__ srcs) {
  __shared__ int hist[512];
  __shared__ int lofs[512];
  __shared__ int sbuf[256];
  const int b = blockIdx.x;
  const int tid = threadIdx.x;
  const int tbeg = b * BCAP;
  const int tend = gcur[b];
  const int base = bktbase[b];
  hist[tid] = 0;
  hist[tid + 256] = 0;
  __syncthreads();
  for (int j = tbeg + tid; j < tend; j += 256) atomicAdd(&hist[tmp[j] & 511], 1);
  __syncthreads();
  int a0 = hist[2 * tid], a1 = hist[2 * tid + 1];
  int sv = a0 + a1;
  sbuf[tid] = sv;
  __syncthreads();
#pragma unroll
  for (int off = 1; off < 256; off <<= 1) {
    int t = (tid >= off) ? sbuf[tid - off] : 0;
    __syncthreads();
    sbuf[tid] += t;
    __syncthreads();
  }
  int excl = sbuf[tid] - sv;
  lofs[2 * tid] = excl;
  lofs[2 * tid + 1] = excl + a0;
  __syncthreads();
  for (int i = tid; i < 512; i += 256) {
    int node = (b << 9) + i;
    if (node < NN) {
      rowptr[node] = base + lofs[i];
      dinv[node] = rsqrtf((float)(hist[i] + 1));
    }
  }
  __syncthreads();
  for (int j = tbeg + tid; j < tend; j += 256) {
    unsigned v = tmp[j];
    int p = base + atomicAdd(&lofs[v & 511], 1);
    srcs[p] = (int)(v >> 9);
  }
}

// One-shot: W[128][N] fp32 -> Wt[n][k] fp16 (k contiguous, stride 128)
template <int N>
__global__ void k_wt(const float* __restrict__ W, _Float16* __restrict__ Wt) {
  int i = blockIdx.x * 256 + threadIdx.x;
  if (i >= 128 * N) return;
  int n = i >> 7, k = i & 127;
  Wt[i] = (_Float16)W[k * N + n];
}

// C[M,N] = A[M,128] @ W[128,N] via mfma_f32_16x16x32_f16, fp16 out.
// Block: 256 thr (4 waves), 64 rows x N cols. A fp32 or fp16 (AHALF), opt ReLU.
template <int N, bool RELU, bool AHALF>
__global__ __launch_bounds__(256) void k_gemm_mfma(const void* __restrict__ Av,
                                                   const _Float16* __restrict__ Wt,
                                                   _Float16* __restrict__ out, int M) {
  constexpr int NF = N / 16;
  __shared__ _Float16 As[64 * 136];
  __shared__ _Float16 Bs[N * 136];
  const int tid = threadIdx.x;
  const long long row0 = (long long)blockIdx.x * 64;
  if (AHALF) {
    const _Float16* A = (const _Float16*)Av;
#pragma unroll
    for (int t = 0; t < 4; ++t) {
      int i = tid + t * 256;  // 1024 uint4 (8 halves each)
      int m = i >> 4, q = i & 15;
      long long row = row0 + m;
      uint4 v = make_uint4(0, 0, 0, 0);
      if (row < M) v = ((const uint4*)A)[row * 16 + q];
      if (RELU) {
        unsigned* pw = (unsigned*)&v;
#pragma unroll
        for (int j = 0; j < 4; ++j) {
          unsigned u = pw[j];
          unsigned lo = (u & 0x8000u) ? 0u : (u & 0xffffu);
          unsigned hi = (u & 0x80000000u) ? 0u : (u & 0xffff0000u);
          pw[j] = lo | hi;
        }
      }
      *(uint4*)&As[m * 136 + q * 8] = v;
    }
  } else {
    const float* A = (const float*)Av;
#pragma unroll
    for (int t = 0; t < 8; ++t) {
      int i = tid + t * 256;  // 2048 float4
      int m = i >> 5, q = i & 31;
      long long row = row0 + m;
      float4 v = make_float4(0.f, 0.f, 0.f, 0.f);
      if (row < M) v = ((const float4*)A)[row * 32 + q];
      if (RELU) {
        v.x = fmaxf(v.x, 0.f); v.y = fmaxf(v.y, 0.f);
        v.z = fmaxf(v.z, 0.f); v.w = fmaxf(v.w, 0.f);
      }
      uint2 w2 = make_uint2(packh2(v.x, v.y), packh2(v.z, v.w));
      *(uint2*)&As[m * 136 + q * 4] = w2;
    }
  }
#pragma unroll
  for (int t = 0; t < N / 16; ++t) {  // N*128 halves / 8 / 256
    int i = tid + t * 256;
    int n = i >> 4, q = i & 15;
    uint4 v = ((const uint4*)Wt)[i];
    *(uint4*)&Bs[n * 136 + q * 8] = v;
  }
  __syncthreads();
  const int lane = tid & 63;
  const int wrow = (tid >> 6) * 16;
  const int r = lane & 15, g = lane >> 4;
  f32x4 acc[NF] = {};
#pragma unroll
  for (int ks = 0; ks < 4; ++ks) {
    f16x8 av = *(const f16x8*)&As[(wrow + r) * 136 + ks * 32 + g * 8];
#pragma unroll
    for (int cf = 0; cf < NF; ++cf) {
      f16x8 bv = *(const f16x8*)&Bs[(cf * 16 + r) * 136 + ks * 32 + g * 8];
      acc[cf] = __builtin_amdgcn_mfma_f32_16x16x32_f16(av, bv, acc[cf], 0, 0, 0);
    }
  }
#pragma unroll
  for (int cf = 0; cf < NF; ++cf) {
#pragma unroll
    for (int q = 0; q < 4; ++q) {
      long long row = row0 + wrow + g * 4 + q;
      if (row < M) out[row * N + cf * 16 + r] = (_Float16)acc[cf][q];
    }
  }
}

// Gather-reduce per node from fp16 h:
// out[d] = dinv[d]*(sum_{s in in(d)} dinv[s]*h[s] + dinv[d]*h[d]) + b
// HOUT: fp16 output (layer 1), else fp32 (final).
template <int C, bool HOUT>
__global__ __launch_bounds__(256) void k_gather_h(const int* __restrict__ rowptr,
                                                  const int* __restrict__ srcs,
                                                  const float* __restrict__ dinv,
                                                  const _Float16* __restrict__ h,
                                                  const float* __restrict__ b,
                                                  void* __restrict__ outv) {
  constexpr int LPN = C / 8;      // lanes per node
  constexpr int NPW = 64 / LPN;   // nodes per wave
  constexpr int NPB = NPW * 4;    // nodes per block
  const int wave = threadIdx.x >> 6;
  const int lane = threadIdx.x & 63;
  const int grp = lane / LPN;
  const int li = lane % LPN;
  const int node = blockIdx.x * NPB + wave * NPW + grp;
  if (node >= NN) return;
  const float dd = dinv[node];
  float acc[8];
  {
    uint4 q = *(const uint4*)(h + (long long)node * C + li * 8);
    const __half2* p = (const __half2*)&q;
#pragma unroll
    for (int j = 0; j < 4; ++j) {
      float2 f = __half22float2(p[j]);
      acc[2 * j]     = dd * f.x;
      acc[2 * j + 1] = dd * f.y;
    }
  }
  const int beg = rowptr[node], end = rowptr[node + 1];
  int e = beg;
  for (; e + 2 <= end; e += 2) {
    int s0 = srcs[e], s1 = srcs[e + 1];
    float w0 = dinv[s0], w1 = dinv[s1];
    uint4 q0 = *(const uint4*)(h + (long long)s0 * C + li * 8);
    uint4 q1 = *(const uint4*)(h + (long long)s1 * C + li * 8);
    acc8(acc, w0, q0);
    acc8(acc, w1, q1);
  }
  if (e < end) {
    int s0 = srcs[e];
    float w0 = dinv[s0];
    uint4 q0 = *(const uint4*)(h + (long long)s0 * C + li * 8);
    acc8(acc, w0, q0);
  }
  const float4* b4 = (const float4*)b;
  float4 bb0 = b4[li * 2], bb1 = b4[li * 2 + 1];
  float o[8];
  o[0] = fmaf(dd, acc[0], bb0.x);
  o[1] = fmaf(dd, acc[1], bb0.y);
  o[2] = fmaf(dd, acc[2], bb0.z);
  o[3] = fmaf(dd, acc[3], bb0.w);
  o[4] = fmaf(dd, acc[4], bb1.x);
  o[5] = fmaf(dd, acc[5], bb1.y);
  o[6] = fmaf(dd, acc[6], bb1.z);
  o[7] = fmaf(dd, acc[7], bb1.w);
  if (HOUT) {
    uint4 w;
    w.x = packh2(o[0], o[1]);
    w.y = packh2(o[2], o[3]);
    w.z = packh2(o[4], o[5]);
    w.w = packh2(o[6], o[7]);
    *(uint4*)((_Float16*)outv + (long long)node * C + li * 8) = w;
  } else {
    float4* op = (float4*)((float*)outv + (long long)node * C + li * 8);
    op[0] = make_float4(o[0], o[1], o[2], o[3]);
    op[1] = make_float4(o[4], o[5], o[6], o[7]);
  }
}

// ---------------- fallback (atomic scatter, fp32) kernels ----------------
__global__ void k_zero_i32(int* p, int n) {
  int i = blockIdx.x * 256 + threadIdx.x;
  if (i < n) p[i] = 0;
}

__global__ void k_deg_count(const int* __restrict__ e, const int* __restrict__ flag,
                            int* __restrict__ deg, int E) {
  int i = blockIdx.x * 256 + threadIdx.x;
  if (i >= E) return;
  int m = *flag;
  int d = m ? e[2 * (E + i)] : e[E + i];
  atomicAdd(&deg[d], 1);
}

__global__ void k_dinv_f(const int* __restrict__ deg, float* __restrict__ dinv) {
  int i = blockIdx.x * 256 + threadIdx.x;
  if (i < NN) dinv[i] = rsqrtf((float)(deg[i] + 1));
}

template <int N, bool RELU>
__global__ __launch_bounds__(256) void k_gemm_v(const float* __restrict__ A,
                                                const float* __restrict__ W,
                                                float* __restrict__ out, int M) {
  constexpr int K4 = 32;
  constexpr int N4 = N / 4;
  constexpr int CG = N4;
  constexpr int ROWS = (256 / CG) * 4;
  __shared__ float4 Wl[128 * N4];
  __shared__ float4 Xl[ROWS * K4];
  const int tid = threadIdx.x;
  const float4* W4 = (const float4*)W;
  for (int i = tid; i < 128 * N4; i += 256) Wl[i] = W4[i];
  const long long row0 = (long long)blockIdx.x * ROWS;
  const float4* A4 = (const float4*)A;
  for (int i = tid; i < ROWS * K4; i += 256) {
    int r = i >> 5;
    long long row = row0 + r;
    float4 v = make_float4(0.f, 0.f, 0.f, 0.f);
    if (row < M) v = A4[row * K4 + (i & 31)];
    if (RELU) {
      v.x = fmaxf(v.x, 0.f); v.y = fmaxf(v.y, 0.f);
      v.z = fmaxf(v.z, 0.f); v.w = fmaxf(v.w, 0.f);
    }
    Xl[i] = v;
  }
  __syncthreads();
  const int c = tid % CG;
  const int rb = (tid / CG) * 4;
  float4 a0 = make_float4(0, 0, 0, 0), a1 = a0, a2 = a0, a3 = a0;
#pragma unroll 4
  for (int k4 = 0; k4 < K4; ++k4) {
    float4 w0 = Wl[(k4 * 4 + 0) * N4 + c];
    float4 w1 = Wl[(k4 * 4 + 1) * N4 + c];
    float4 w2 = Wl[(k4 * 4 + 2) * N4 + c];
    float4 w3 = Wl[(k4 * 4 + 3) * N4 + c];
    float4 x0 = Xl[(rb + 0) * K4 + k4];
    float4 x1 = Xl[(rb + 1) * K4 + k4];
    float4 x2 = Xl[(rb + 2) * K4 + k4];
    float4 x3 = Xl[(rb + 3) * K4 + k4];
    fma4(a0, x0.x, w0); fma4(a0, x0.y, w1); fma4(a0, x0.z, w2); fma4(a0, x0.w, w3);
    fma4(a1, x1.x, w0); fma4(a1, x1.y, w1); fma4(a1, x1.z, w2); fma4(a1, x1.w, w3);
    fma4(a2, x2.x, w0); fma4(a2, x2.y, w1); fma4(a2, x2.z, w2); fma4(a2, x2.w, w3);
    fma4(a3, x3.x, w0); fma4(a3, x3.y, w1); fma4(a3, x3.z, w2); fma4(a3, x3.w, w3);
  }
  float4* O4 = (float4*)out;
  long long row = row0 + rb;
  if (row + 0 < M) O4[(row + 0) * N4 + c] = a0;
  if (row + 1 < M) O4[(row + 1) * N4 + c] = a1;
  if (row + 2 < M) O4[(row + 2) * N4 + c] = a2;
  if (row + 3 < M) O4[(row + 3) * N4 + c] = a3;
}

template <int C>
__global__ void k_self_bias(const float* __restrict__ h, const float* __restrict__ dinv,
                            const float* __restrict__ b, float* __restrict__ out) {
  constexpr int C4 = C / 4;
  int gid = blockIdx.x * 256 + threadIdx.x;
  if (gid >= NN * C4) return;
  int node = gid / C4;
  int cq = gid % C4;
  float di = dinv[node];
  float sc = di * di;
  float4 v = ((const float4*)h)[gid];
  float4 bb = ((const float4*)b)[cq];
  float4 o;
  o.x = fmaf(v.x, sc, bb.x);
  o.y = fmaf(v.y, sc, bb.y);
  o.z = fmaf(v.z, sc, bb.z);
  o.w = fmaf(v.w, sc, bb.w);
  ((float4*)out)[gid] = o;
}

template <int C>
__global__ void k_scatter(const int* __restrict__ e, const int* __restrict__ flag,
                          const float* __restrict__ dinv, const float* __restrict__ h,
                          float* __restrict__ out, int E) {
  constexpr int TPE = C / 4;
  long long gid = (long long)blockIdx.x * blockDim.x + threadIdx.x;
  int ei = (int)(gid / TPE);
  int cq = (int)(gid % TPE);
  if (ei >= E) return;
  int m = *flag;
  int s, d;
  if (m) { s = e[2 * ei]; d = e[2 * (E + ei)]; }
  else   { s = e[ei];     d = e[E + ei]; }
  float nrm = dinv[s] * dinv[d];
  float4 v = ((const float4*)h)[(long long)s * TPE + cq];
  float* op = out + (long long)d * C + (long long)cq * 4;
  unsafeAtomicAdd(op + 0, v.x * nrm);
  unsafeAtomicAdd(op + 1, v.y * nrm);
  unsafeAtomicAdd(op + 2, v.z * nrm);
  unsafeAtomicAdd(op + 3, v.w * nrm);
}

extern "C" void kernel_launch(void* const* d_in, const int* in_sizes, int n_in,
                              void* d_out, int out_size, void* d_ws, size_t ws_size,
                              hipStream_t stream) {
  const float* x  = (const float*)d_in[0];
  const int*   e  = (const int*)d_in[1];
  const float* W1 = (const float*)d_in[2];
  const float* b1 = (const float*)d_in[3];
  const float* W2 = (const float*)d_in[4];
  const float* b2 = (const float*)d_in[5];
  float* out = (float*)d_out;
  const int E = in_sizes[1] / 2;

  char* ws = (char*)d_ws;
  const size_t o_flag    = 0;         // 16
  const size_t o_dinv    = 16;        // 400,000
  const size_t o_rowptr  = 400016;    // 400,004 (NN+1)
  const size_t o_gcur    = 800032;    // 784
  const size_t o_bktbase = 800832;    // 788 (NBKT+1)
  const size_t o_tmp     = 801632;    // 196*16384*4 = 12,845,056
  const size_t o_srcs    = 13646688;  // 6,400,000
  const size_t o_wt1     = 20046688;  // 32,768
  const size_t o_wt2     = 20079456;  // 16,384
  const size_t o_h       = 20095840;  // fp16 h: 25,600,000
  const size_t o_out1    = 45695840;  // fp16 out1: 25,600,000
  const size_t need_csr  = 71295840;

  int*      flag    = (int*)(ws + o_flag);
  float*    dinv    = (float*)(ws + o_dinv);
  int*      rowptr  = (int*)(ws + o_rowptr);
  int*      gcur    = (int*)(ws + o_gcur);
  int*      bktbase = (int*)(ws + o_bktbase);
  unsigned* tmp     = (unsigned*)(ws + o_tmp);
  int*      srcs    = (int*)(ws + o_srcs);
  _Float16* wt1     = (_Float16*)(ws + o_wt1);
  _Float16* wt2     = (_Float16*)(ws + o_wt2);
  _Float16* hh      = (_Float16*)(ws + o_h);
  _Float16* out1    = (_Float16*)(ws + o_out1);

  k_detect<<<1, 64, 0, stream>>>(e, flag, E);

  if (ws_size >= need_csr) {
    // ---- CSR gather path: binned build, fp16 messages, MFMA GEMMs ----
    k_gcur_init<<<1, 256, 0, stream>>>(gcur);
    k_wt<128><<<64, 256, 0, stream>>>(W1, wt1);
    k_wt<64><<<32, 256, 0, stream>>>(W2, wt2);
    k_binA<<<(E + 4095) / 4096, 256, 0, stream>>>(e, flag, gcur, tmp, E);
    k_bkt_scan<<<1, 256, 0, stream>>>(gcur, bktbase, rowptr);
    k_binB<<<NBKT, 256, 0, stream>>>(tmp, gcur, bktbase, rowptr, dinv, srcs);

    k_gemm_mfma<128, false, false><<<(NN + 63) / 64, 256, 0, stream>>>(x, wt1, hh, NN);
    k_gather_h<128, true><<<(NN + 15) / 16, 256, 0, stream>>>(rowptr, srcs, dinv, hh, b1, out1);

    k_gemm_mfma<64, true, true><<<(NN + 63) / 64, 256, 0, stream>>>(out1, wt2, hh, NN);
    k_gather_h<64, false><<<(NN + 31) / 32, 256, 0, stream>>>(rowptr, srcs, dinv, hh, b2, out);
  } else {
    // ---- fallback: fp32 atomic scatter path ----
    int*   deg   = (int*)(ws + 400016);
    float* hF    = (float*)(ws + (1 << 20));
    float* out1F = (float*)(ws + (1 << 20) + 51200000);
    k_zero_i32<<<(NN + 255) / 256, 256, 0, stream>>>(deg, NN);
    k_deg_count<<<(E + 255) / 256, 256, 0, stream>>>(e, flag, deg, E);
    k_dinv_f<<<(NN + 255) / 256, 256, 0, stream>>>(deg, dinv);
    k_gemm_v<128, false><<<(NN + 31) / 32, 256, 0, stream>>>(x, W1, hF, NN);
    k_self_bias<128><<<(NN * 32 + 255) / 256, 256, 0, stream>>>(hF, dinv, b1, out1F);
    long long tot1 = (long long)E * 32;
    k_scatter<128><<<(int)((tot1 + 255) / 256), 256, 0, stream>>>(e, flag, dinv, hF, out1F, E);
    k_gemm_v<64, true><<<(NN + 63) / 64, 256, 0, stream>>>(out1F, W2, hF, NN);
    k_self_bias<64><<<(NN * 16 + 255) / 256, 256, 0, stream>>>(hF, dinv, b2, out);
    long long tot2 = (long long)E * 16;
    k_scatter<64><<<(int)((tot2 + 255) / 256), 256, 0, stream>>>(e, flag, dinv, hF, out, E);
  }
}

// Round 7
// 224.198 us; speedup vs baseline: 18.9459x; 1.0460x over previous
//
#include <hip/hip_runtime.h>
#include <hip/hip_fp16.h>

#define NN 100000
#define NBKT 196   // ceil(NN/512)
#define BCAP 16384 // slack per bucket (mean 8192, sigma ~90)

using f16x8 = __attribute__((ext_vector_type(8))) _Float16;
using f32x4 = __attribute__((ext_vector_type(4))) float;

// ---------------- helpers ----------------
__device__ __forceinline__ void fma4(float4& a, float s, const float4& w) {
  a.x = fmaf(s, w.x, a.x);
  a.y = fmaf(s, w.y, a.y);
  a.z = fmaf(s, w.z, a.z);
  a.w = fmaf(s, w.w, a.w);
}

// a[0..8) += cvt(8 halves)
__device__ __forceinline__ void add8(float* a, uint4 q) {
  const __half2* p = (const __half2*)&q;
#pragma unroll
  for (int j = 0; j < 4; ++j) {
    float2 f = __half22float2(p[j]);
    a[2 * j]     += f.x;
    a[2 * j + 1] += f.y;
  }
}

__device__ __forceinline__ unsigned packh2(float x, float y) {
  __half2 h = __floats2half2_rn(x, y);
  return *(unsigned*)&h;
}

// Fused setup: wt1 (blocks 0-63), wt2 (64-95), gcur init + int64-detect (96).
__global__ __launch_bounds__(256) void k_prep(const float* __restrict__ W1,
                                              const float* __restrict__ W2,
                                              _Float16* __restrict__ wt1,
                                              _Float16* __restrict__ wt2,
                                              int* __restrict__ gcur,
                                              const int* __restrict__ e,
                                              int* __restrict__ flag, int E) {
  const int b = blockIdx.x;
  const int tid = threadIdx.x;
  if (b < 64) {                       // wt1: 128x128 -> [n][k] fp16
    int i = b * 256 + tid;
    int n = i >> 7, k = i & 127;
    wt1[i] = (_Float16)W1[k * 128 + n];
  } else if (b < 96) {                // wt2: 128x64 -> [n][k] fp16
    int i = (b - 64) * 256 + tid;
    int n = i >> 7, k = i & 127;
    wt2[i] = (_Float16)W2[k * 64 + n];
  } else {
    if (tid < NBKT) gcur[tid] = tid * BCAP;
    if (tid == 255) {
      int n = E < 64 ? E : 64;
      int m = 1;
      for (int i = 0; i < n; ++i)
        if (e[2 * i + 1] != 0) { m = 0; break; }
      *flag = m;
    }
  }
}

// Stage A: bin edges into NBKT dst-buckets (512 nodes each), slack regions.
__global__ __launch_bounds__(256) void k_binA(const int* __restrict__ e,
                                              const int* __restrict__ flag,
                                              int* __restrict__ gcur,
                                              unsigned int* __restrict__ tmp, int E) {
  __shared__ int cnt[256];
  __shared__ int pcur[256];
  const int tid = threadIdx.x;
  const int start = blockIdx.x * 4096;
  const int m = *flag;
  cnt[tid] = 0;
  __syncthreads();
  int ss[16], dd[16];
#pragma unroll
  for (int k = 0; k < 16; ++k) {
    int i = start + tid + k * 256;
    int s = -1, d = 0;
    if (i < E) {
      if (m) {
        s = (int)((const long long*)e)[i];
        d = (int)((const long long*)e)[E + i];
      } else {
        s = e[i];
        d = e[E + i];
      }
      atomicAdd(&cnt[d >> 9], 1);
    }
    ss[k] = s; dd[k] = d;
  }
  __syncthreads();
  if (tid < NBKT && cnt[tid] > 0) pcur[tid] = atomicAdd(&gcur[tid], cnt[tid]);
  __syncthreads();
#pragma unroll
  for (int k = 0; k < 16; ++k) {
    if (ss[k] >= 0) {
      int b = dd[k] >> 9;
      int p = atomicAdd(&pcur[b], 1);
      tmp[p] = ((unsigned)ss[k] << 9) | (unsigned)(dd[k] & 511);
    }
  }
}

// Exclusive scan of per-bucket totals -> bktbase; rowptr[NN]=total.
__global__ __launch_bounds__(256) void k_bkt_scan(const int* __restrict__ gcur,
                                                  int* __restrict__ bktbase,
                                                  int* __restrict__ rowptr) {
  __shared__ int s[256];
  const int tid = threadIdx.x;
  int v = (tid < NBKT) ? (gcur[tid] - tid * BCAP) : 0;
  s[tid] = v;
  __syncthreads();
#pragma unroll
  for (int off = 1; off < 256; off <<= 1) {
    int t = (tid >= off) ? s[tid - off] : 0;
    __syncthreads();
    s[tid] += t;
    __syncthreads();
  }
  if (tid < NBKT) bktbase[tid] = s[tid] - v;
  if (tid == 255) {
    bktbase[NBKT] = s[255];
    rowptr[NN] = s[255];
  }
}

// Stage B: per bucket: LDS histogram (= deg) -> dinv + rowptr, local scan,
// then place srcs into the bucket's contiguous window.
__global__ __launch_bounds__(256) void k_binB(const unsigned int* __restrict__ tmp,
                                              const int* __restrict__ gcur,
                                              const int* __restrict__ bktbase,
                                              int* __restrict__ rowptr,
                                              float* __restrict__ dinv,
                                              int* __restrict__ srcs) {
  __shared__ int hist[512];
  __shared__ int lofs[512];
  __shared__ int sbuf[256];
  const int b = blockIdx.x;
  const int tid = threadIdx.x;
  const int tbeg = b * BCAP;
  const int tend = gcur[b];
  const int base = bktbase[b];
  hist[tid] = 0;
  hist[tid + 256] = 0;
  __syncthreads();
  for (int j = tbeg + tid; j < tend; j += 256) atomicAdd(&hist[tmp[j] & 511], 1);
  __syncthreads();
  int a0 = hist[2 * tid], a1 = hist[2 * tid + 1];
  int sv = a0 + a1;
  sbuf[tid] = sv;
  __syncthreads();
#pragma unroll
  for (int off = 1; off < 256; off <<= 1) {
    int t = (tid >= off) ? sbuf[tid - off] : 0;
    __syncthreads();
    sbuf[tid] += t;
    __syncthreads();
  }
  int excl = sbuf[tid] - sv;
  lofs[2 * tid] = excl;
  lofs[2 * tid + 1] = excl + a0;
  __syncthreads();
  for (int i = tid; i < 512; i += 256) {
    int node = (b << 9) + i;
    if (node < NN) {
      rowptr[node] = base + lofs[i];
      dinv[node] = rsqrtf((float)(hist[i] + 1));
    }
  }
  __syncthreads();
  for (int j = tbeg + tid; j < tend; j += 256) {
    unsigned v = tmp[j];
    int p = base + atomicAdd(&lofs[v & 511], 1);
    srcs[p] = (int)(v >> 9);
  }
}

// C[M,N] = A[M,128] @ W[128,N] via mfma_f32_16x16x32_f16.
// Epilogue scales row by dinv[row] (pre-scaled message table), fp16 out.
template <int N, bool AHALF>
__global__ __launch_bounds__(256) void k_gemm_mfma(const void* __restrict__ Av,
                                                   const _Float16* __restrict__ Wt,
                                                   const float* __restrict__ dinv,
                                                   _Float16* __restrict__ out, int M) {
  constexpr int NF = N / 16;
  __shared__ _Float16 As[64 * 136];
  __shared__ _Float16 Bs[N * 136];
  const int tid = threadIdx.x;
  const long long row0 = (long long)blockIdx.x * 64;
  if (AHALF) {
    const _Float16* A = (const _Float16*)Av;
#pragma unroll
    for (int t = 0; t < 4; ++t) {
      int i = tid + t * 256;  // 1024 uint4 (8 halves each)
      int m = i >> 4, q = i & 15;
      long long row = row0 + m;
      uint4 v = make_uint4(0, 0, 0, 0);
      if (row < M) v = ((const uint4*)A)[row * 16 + q];
      *(uint4*)&As[m * 136 + q * 8] = v;
    }
  } else {
    const float* A = (const float*)Av;
#pragma unroll
    for (int t = 0; t < 8; ++t) {
      int i = tid + t * 256;  // 2048 float4
      int m = i >> 5, q = i & 31;
      long long row = row0 + m;
      float4 v = make_float4(0.f, 0.f, 0.f, 0.f);
      if (row < M) v = ((const float4*)A)[row * 32 + q];
      uint2 w2 = make_uint2(packh2(v.x, v.y), packh2(v.z, v.w));
      *(uint2*)&As[m * 136 + q * 4] = w2;
    }
  }
#pragma unroll
  for (int t = 0; t < N / 16; ++t) {
    int i = tid + t * 256;
    int n = i >> 4, q = i & 15;
    uint4 v = ((const uint4*)Wt)[i];
    *(uint4*)&Bs[n * 136 + q * 8] = v;
  }
  __syncthreads();
  const int lane = tid & 63;
  const int wrow = (tid >> 6) * 16;
  const int r = lane & 15, g = lane >> 4;
  f32x4 acc[NF] = {};
#pragma unroll
  for (int ks = 0; ks < 4; ++ks) {
    f16x8 av = *(const f16x8*)&As[(wrow + r) * 136 + ks * 32 + g * 8];
#pragma unroll
    for (int cf = 0; cf < NF; ++cf) {
      f16x8 bv = *(const f16x8*)&Bs[(cf * 16 + r) * 136 + ks * 32 + g * 8];
      acc[cf] = __builtin_amdgcn_mfma_f32_16x16x32_f16(av, bv, acc[cf], 0, 0, 0);
    }
  }
#pragma unroll
  for (int q = 0; q < 4; ++q) {
    long long row = row0 + wrow + g * 4 + q;
    if (row < M) {
      float sc = dinv[row];
#pragma unroll
      for (int cf = 0; cf < NF; ++cf)
        out[row * N + cf * 16 + r] = (_Float16)(sc * acc[cf][q]);
    }
  }
}

// Gather-reduce over pre-scaled table: out[d] = dd * (sum rows incl. self) + b.
// RELU16: relu + fp16 out (layer 1); else fp32 out (final).
template <int C, bool RELU16>
__global__ __launch_bounds__(256) void k_gather_s(const int* __restrict__ rowptr,
                                                  const int* __restrict__ srcs,
                                                  const float* __restrict__ dinv,
                                                  const _Float16* __restrict__ h,
                                                  const float* __restrict__ b,
                                                  void* __restrict__ outv) {
  constexpr int LPN = C / 8;      // lanes per node
  constexpr int NPW = 64 / LPN;   // nodes per wave
  constexpr int NPB = NPW * 4;    // nodes per block
  const int wave = threadIdx.x >> 6;
  const int lane = threadIdx.x & 63;
  const int grp = lane / LPN;
  const int li = lane % LPN;
  const int node = blockIdx.x * NPB + wave * NPW + grp;
  if (node >= NN) return;
  const float dd = dinv[node];
  float acc[8];
  {
    // self message: scaled[d] = dinv[d]*h[d] exactly
    uint4 q = *(const uint4*)(h + (long long)node * C + li * 8);
    const __half2* p = (const __half2*)&q;
#pragma unroll
    for (int j = 0; j < 4; ++j) {
      float2 f = __half22float2(p[j]);
      acc[2 * j]     = f.x;
      acc[2 * j + 1] = f.y;
    }
  }
  const int beg = rowptr[node], end = rowptr[node + 1];
  int e = beg;
  for (; e + 4 <= end; e += 4) {
    int s0 = srcs[e], s1 = srcs[e + 1], s2 = srcs[e + 2], s3 = srcs[e + 3];
    uint4 q0 = *(const uint4*)(h + (long long)s0 * C + li * 8);
    uint4 q1 = *(const uint4*)(h + (long long)s1 * C + li * 8);
    uint4 q2 = *(const uint4*)(h + (long long)s2 * C + li * 8);
    uint4 q3 = *(const uint4*)(h + (long long)s3 * C + li * 8);
    add8(acc, q0);
    add8(acc, q1);
    add8(acc, q2);
    add8(acc, q3);
  }
  for (; e < end; ++e) {
    uint4 q0 = *(const uint4*)(h + (long long)srcs[e] * C + li * 8);
    add8(acc, q0);
  }
  const float4* b4 = (const float4*)b;
  float4 bb0 = b4[li * 2], bb1 = b4[li * 2 + 1];
  float o[8];
  o[0] = fmaf(dd, acc[0], bb0.x);
  o[1] = fmaf(dd, acc[1], bb0.y);
  o[2] = fmaf(dd, acc[2], bb0.z);
  o[3] = fmaf(dd, acc[3], bb0.w);
  o[4] = fmaf(dd, acc[4], bb1.x);
  o[5] = fmaf(dd, acc[5], bb1.y);
  o[6] = fmaf(dd, acc[6], bb1.z);
  o[7] = fmaf(dd, acc[7], bb1.w);
  if (RELU16) {
#pragma unroll
    for (int j = 0; j < 8; ++j) o[j] = fmaxf(o[j], 0.f);
    uint4 w;
    w.x = packh2(o[0], o[1]);
    w.y = packh2(o[2], o[3]);
    w.z = packh2(o[4], o[5]);
    w.w = packh2(o[6], o[7]);
    *(uint4*)((_Float16*)outv + (long long)node * C + li * 8) = w;
  } else {
    float4* op = (float4*)((float*)outv + (long long)node * C + li * 8);
    op[0] = make_float4(o[0], o[1], o[2], o[3]);
    op[1] = make_float4(o[4], o[5], o[6], o[7]);
  }
}

// ---------------- fallback (atomic scatter, fp32) kernels ----------------
__global__ void k_zero_i32(int* p, int n) {
  int i = blockIdx.x * 256 + threadIdx.x;
  if (i < n) p[i] = 0;
}

__global__ void k_detect_f(const int* __restrict__ e, int* flag, int E) {
  if (threadIdx.x == 0 && blockIdx.x == 0) {
    int n = E < 64 ? E : 64;
    int m = 1;
    for (int i = 0; i < n; ++i)
      if (e[2 * i + 1] != 0) { m = 0; break; }
    *flag = m;
  }
}

__global__ void k_deg_count(const int* __restrict__ e, const int* __restrict__ flag,
                            int* __restrict__ deg, int E) {
  int i = blockIdx.x * 256 + threadIdx.x;
  if (i >= E) return;
  int m = *flag;
  int d = m ? e[2 * (E + i)] : e[E + i];
  atomicAdd(&deg[d], 1);
}

__global__ void k_dinv_f(const int* __restrict__ deg, float* __restrict__ dinv) {
  int i = blockIdx.x * 256 + threadIdx.x;
  if (i < NN) dinv[i] = rsqrtf((float)(deg[i] + 1));
}

template <int N, bool RELU>
__global__ __launch_bounds__(256) void k_gemm_v(const float* __restrict__ A,
                                                const float* __restrict__ W,
                                                float* __restrict__ out, int M) {
  constexpr int K4 = 32;
  constexpr int N4 = N / 4;
  constexpr int CG = N4;
  constexpr int ROWS = (256 / CG) * 4;
  __shared__ float4 Wl[128 * N4];
  __shared__ float4 Xl[ROWS * K4];
  const int tid = threadIdx.x;
  const float4* W4 = (const float4*)W;
  for (int i = tid; i < 128 * N4; i += 256) Wl[i] = W4[i];
  const long long row0 = (long long)blockIdx.x * ROWS;
  const float4* A4 = (const float4*)A;
  for (int i = tid; i < ROWS * K4; i += 256) {
    int r = i >> 5;
    long long row = row0 + r;
    float4 v = make_float4(0.f, 0.f, 0.f, 0.f);
    if (row < M) v = A4[row * K4 + (i & 31)];
    if (RELU) {
      v.x = fmaxf(v.x, 0.f); v.y = fmaxf(v.y, 0.f);
      v.z = fmaxf(v.z, 0.f); v.w = fmaxf(v.w, 0.f);
    }
    Xl[i] = v;
  }
  __syncthreads();
  const int c = tid % CG;
  const int rb = (tid / CG) * 4;
  float4 a0 = make_float4(0, 0, 0, 0), a1 = a0, a2 = a0, a3 = a0;
#pragma unroll 4
  for (int k4 = 0; k4 < K4; ++k4) {
    float4 w0 = Wl[(k4 * 4 + 0) * N4 + c];
    float4 w1 = Wl[(k4 * 4 + 1) * N4 + c];
    float4 w2 = Wl[(k4 * 4 + 2) * N4 + c];
    float4 w3 = Wl[(k4 * 4 + 3) * N4 + c];
    float4 x0 = Xl[(rb + 0) * K4 + k4];
    float4 x1 = Xl[(rb + 1) * K4 + k4];
    float4 x2 = Xl[(rb + 2) * K4 + k4];
    float4 x3 = Xl[(rb + 3) * K4 + k4];
    fma4(a0, x0.x, w0); fma4(a0, x0.y, w1); fma4(a0, x0.z, w2); fma4(a0, x0.w, w3);
    fma4(a1, x1.x, w0); fma4(a1, x1.y, w1); fma4(a1, x1.z, w2); fma4(a1, x1.w, w3);
    fma4(a2, x2.x, w0); fma4(a2, x2.y, w1); fma4(a2, x2.z, w2); fma4(a2, x2.w, w3);
    fma4(a3, x3.x, w0); fma4(a3, x3.y, w1); fma4(a3, x3.z, w2); fma4(a3, x3.w, w3);
  }
  float4* O4 = (float4*)out;
  long long row = row0 + rb;
  if (row + 0 < M) O4[(row + 0) * N4 + c] = a0;
  if (row + 1 < M) O4[(row + 1) * N4 + c] = a1;
  if (row + 2 < M) O4[(row + 2) * N4 + c] = a2;
  if (row + 3 < M) O4[(row + 3) * N4 + c] = a3;
}

template <int C>
__global__ void k_self_bias(const float* __restrict__ h, const float* __restrict__ dinv,
                            const float* __restrict__ b, float* __restrict__ out) {
  constexpr int C4 = C / 4;
  int gid = blockIdx.x * 256 + threadIdx.x;
  if (gid >= NN * C4) return;
  int node = gid / C4;
  int cq = gid % C4;
  float di = dinv[node];
  float sc = di * di;
  float4 v = ((const float4*)h)[gid];
  float4 bb = ((const float4*)b)[cq];
  float4 o;
  o.x = fmaf(v.x, sc, bb.x);
  o.y = fmaf(v.y, sc, bb.y);
  o.z = fmaf(v.z, sc, bb.z);
  o.w = fmaf(v.w, sc, bb.w);
  ((float4*)out)[gid] = o;
}

template <int C>
__global__ void k_scatter(const int* __restrict__ e, const int* __restrict__ flag,
                          const float* __restrict__ dinv, const float* __restrict__ h,
                          float* __restrict__ out, int E) {
  constexpr int TPE = C / 4;
  long long gid = (long long)blockIdx.x * blockDim.x + threadIdx.x;
  int ei = (int)(gid / TPE);
  int cq = (int)(gid % TPE);
  if (ei >= E) return;
  int m = *flag;
  int s, d;
  if (m) { s = e[2 * ei]; d = e[2 * (E + ei)]; }
  else   { s = e[ei];     d = e[E + ei]; }
  float nrm = dinv[s] * dinv[d];
  float4 v = ((const float4*)h)[(long long)s * TPE + cq];
  float* op = out + (long long)d * C + (long long)cq * 4;
  unsafeAtomicAdd(op + 0, v.x * nrm);
  unsafeAtomicAdd(op + 1, v.y * nrm);
  unsafeAtomicAdd(op + 2, v.z * nrm);
  unsafeAtomicAdd(op + 3, v.w * nrm);
}

extern "C" void kernel_launch(void* const* d_in, const int* in_sizes, int n_in,
                              void* d_out, int out_size, void* d_ws, size_t ws_size,
                              hipStream_t stream) {
  const float* x  = (const float*)d_in[0];
  const int*   e  = (const int*)d_in[1];
  const float* W1 = (const float*)d_in[2];
  const float* b1 = (const float*)d_in[3];
  const float* W2 = (const float*)d_in[4];
  const float* b2 = (const float*)d_in[5];
  float* out = (float*)d_out;
  const int E = in_sizes[1] / 2;

  char* ws = (char*)d_ws;
  const size_t o_flag    = 0;         // 16
  const size_t o_dinv    = 16;        // 400,000
  const size_t o_rowptr  = 400016;    // 400,004 (NN+1)
  const size_t o_gcur    = 800032;    // 784
  const size_t o_bktbase = 800832;    // 788 (NBKT+1)
  const size_t o_tmp     = 801632;    // 196*16384*4 = 12,845,056
  const size_t o_srcs    = 13646688;  // 6,400,000
  const size_t o_wt1     = 20046688;  // 32,768
  const size_t o_wt2     = 20079456;  // 16,384
  const size_t o_h       = 20095840;  // fp16 h: 25,600,000
  const size_t o_out1    = 45695840;  // fp16 out1: 25,600,000
  const size_t need_csr  = 71295840;

  int*      flag    = (int*)(ws + o_flag);
  float*    dinv    = (float*)(ws + o_dinv);
  int*      rowptr  = (int*)(ws + o_rowptr);
  int*      gcur    = (int*)(ws + o_gcur);
  int*      bktbase = (int*)(ws + o_bktbase);
  unsigned* tmp     = (unsigned*)(ws + o_tmp);
  int*      srcs    = (int*)(ws + o_srcs);
  _Float16* wt1     = (_Float16*)(ws + o_wt1);
  _Float16* wt2     = (_Float16*)(ws + o_wt2);
  _Float16* hh      = (_Float16*)(ws + o_h);
  _Float16* out1    = (_Float16*)(ws + o_out1);

  if (ws_size >= need_csr) {
    // ---- CSR gather path: pre-scaled fp16 messages, MFMA GEMMs ----
    k_prep<<<97, 256, 0, stream>>>(W1, W2, wt1, wt2, gcur, e, flag, E);
    k_binA<<<(E + 4095) / 4096, 256, 0, stream>>>(e, flag, gcur, tmp, E);
    k_bkt_scan<<<1, 256, 0, stream>>>(gcur, bktbase, rowptr);
    k_binB<<<NBKT, 256, 0, stream>>>(tmp, gcur, bktbase, rowptr, dinv, srcs);

    k_gemm_mfma<128, false><<<(NN + 63) / 64, 256, 0, stream>>>(x, wt1, dinv, hh, NN);
    k_gather_s<128, true><<<(NN + 15) / 16, 256, 0, stream>>>(rowptr, srcs, dinv, hh, b1, out1);

    k_gemm_mfma<64, true><<<(NN + 63) / 64, 256, 0, stream>>>(out1, wt2, dinv, hh, NN);
    k_gather_s<64, false><<<(NN + 31) / 32, 256, 0, stream>>>(rowptr, srcs, dinv, hh, b2, out);
  } else {
    // ---- fallback: fp32 atomic scatter path ----
    int*   deg   = (int*)(ws + 400016);
    float* hF    = (float*)(ws + (1 << 20));
    float* out1F = (float*)(ws + (1 << 20) + 51200000);
    k_detect_f<<<1, 64, 0, stream>>>(e, flag, E);
    k_zero_i32<<<(NN + 255) / 256, 256, 0, stream>>>(deg, NN);
    k_deg_count<<<(E + 255) / 256, 256, 0, stream>>>(e, flag, deg, E);
    k_dinv_f<<<(NN + 255) / 256, 256, 0, stream>>>(deg, dinv);
    k_gemm_v<128, false><<<(NN + 31) / 32, 256, 0, stream>>>(x, W1, hF, NN);
    k_self_bias<128><<<(NN * 32 + 255) / 256, 256, 0, stream>>>(hF, dinv, b1, out1F);
    long long tot1 = (long long)E * 32;
    k_scatter<128><<<(int)((tot1 + 255) / 256), 256, 0, stream>>>(e, flag, dinv, hF, out1F, E);
    k_gemm_v<64, true><<<(NN + 63) / 64, 256, 0, stream>>>(out1F, W2, hF, NN);
    k_self_bias<64><<<(NN * 16 + 255) / 256, 256, 0, stream>>>(hF, dinv, b2, out);
    long long tot2 = (long long)E * 16;
    k_scatter<64><<<(int)((tot2 + 255) / 256), 256, 0, stream>>>(e, flag, dinv, hF, out, E);
  }
}

// Round 8
// 222.685 us; speedup vs baseline: 19.0746x; 1.0068x over previous
//
#include <hip/hip_runtime.h>
#include <hip/hip_fp16.h>

#define NN 100000
#define NBKT 196   // ceil(NN/512)
#define BCAP 16384 // slack per bucket (mean 8163, sigma ~90 for E=1.6M)

using f16x8 = __attribute__((ext_vector_type(8))) _Float16;
using f32x4 = __attribute__((ext_vector_type(4))) float;

// ---------------- helpers ----------------
__device__ __forceinline__ void fma4(float4& a, float s, const float4& w) {
  a.x = fmaf(s, w.x, a.x);
  a.y = fmaf(s, w.y, a.y);
  a.z = fmaf(s, w.z, a.z);
  a.w = fmaf(s, w.w, a.w);
}

// a[0..8) += cvt(8 halves)
__device__ __forceinline__ void add8(float* a, uint4 q) {
  const __half2* p = (const __half2*)&q;
#pragma unroll
  for (int j = 0; j < 4; ++j) {
    float2 f = __half22float2(p[j]);
    a[2 * j]     += f.x;
    a[2 * j + 1] += f.y;
  }
}

__device__ __forceinline__ unsigned packh2(float x, float y) {
  __half2 h = __floats2half2_rn(x, y);
  return *(unsigned*)&h;
}

// Stage A + prep fused.
// blocks [0,nA): bin 4096 edges each into NBKT dst-buckets (slack regions).
// blocks [nA,nA+64): W1 -> wt1 fp16 [n][k].  [nA+64,nA+96): W2 -> wt2.
// int64-vs-int32 detection done per binning block via one ballot.
__global__ __launch_bounds__(256) void k_binA(const int* __restrict__ e,
                                              const float* __restrict__ W1,
                                              const float* __restrict__ W2,
                                              _Float16* __restrict__ wt1,
                                              _Float16* __restrict__ wt2,
                                              int* __restrict__ gcur,
                                              unsigned int* __restrict__ tmp,
                                              int E, int nA) {
  const int b = blockIdx.x;
  const int tid = threadIdx.x;
  if (b >= nA) {  // weight conversion
    int wb = b - nA;
    if (wb < 64) {
      int i = wb * 256 + tid;
      int n = i >> 7, k = i & 127;
      wt1[i] = (_Float16)W1[k * 128 + n];
    } else {
      int i = (wb - 64) * 256 + tid;
      int n = i >> 7, k = i & 127;
      wt2[i] = (_Float16)W2[k * 64 + n];
    }
    return;
  }
  __shared__ int cnt[256];
  __shared__ int pcur[256];
  __shared__ int sm_flag;
  cnt[tid] = 0;
  if (tid < 64) {  // wave 0: detect int64 layout (odd words all zero)
    int n64 = E < 64 ? E : 64;
    int odd = (tid < n64) ? e[2 * tid + 1] : 0;
    unsigned long long nz = __ballot(odd != 0);
    if (tid == 0) sm_flag = (nz == 0ull) ? 1 : 0;
  }
  __syncthreads();
  const int m = sm_flag;
  const bool pok = ((E & 1) == 0);
  const int start = b * 4096;
  int ss[16], dd[16];
#pragma unroll
  for (int k = 0; k < 8; ++k) {
    int i = start + 2 * (tid + k * 256);
    int s0 = -1, s1 = -1, d0 = 0, d1 = 0;
    if (i < E) {
      if (m) {
        if (pok) {
          int4 sp = ((const int4*)e)[i >> 1];
          int4 dp = ((const int4*)e)[(E + i) >> 1];
          s0 = sp.x; s1 = sp.z; d0 = dp.x; d1 = dp.z;
        } else {
          s0 = (int)((const long long*)e)[i];
          d0 = (int)((const long long*)e)[E + i];
          if (i + 1 < E) {
            s1 = (int)((const long long*)e)[i + 1];
            d1 = (int)((const long long*)e)[E + i + 1];
          }
        }
      } else {
        if (pok) {
          int2 sp = ((const int2*)e)[i >> 1];
          int2 dp = ((const int2*)(e + E))[i >> 1];
          s0 = sp.x; s1 = sp.y; d0 = dp.x; d1 = dp.y;
        } else {
          s0 = e[i]; d0 = e[E + i];
          if (i + 1 < E) { s1 = e[i + 1]; d1 = e[E + i + 1]; }
        }
      }
      if (i + 1 >= E) s1 = -1;
      atomicAdd(&cnt[d0 >> 9], 1);
      if (s1 >= 0) atomicAdd(&cnt[d1 >> 9], 1);
    }
    ss[2 * k] = s0; dd[2 * k] = d0;
    ss[2 * k + 1] = s1; dd[2 * k + 1] = d1;
  }
  __syncthreads();
  if (tid < NBKT && cnt[tid] > 0)
    pcur[tid] = tid * BCAP + atomicAdd(&gcur[tid], cnt[tid]);
  __syncthreads();
#pragma unroll
  for (int k = 0; k < 16; ++k) {
    if (ss[k] >= 0) {
      int bk = dd[k] >> 9;
      int p = atomicAdd(&pcur[bk], 1);
      tmp[p] = ((unsigned)ss[k] << 9) | (unsigned)(dd[k] & 511);
    }
  }
}

// Stage B (scan fused): per bucket, redundant 196-count scan -> base/total;
// LDS histogram (= deg) -> dinv + rowptr; local scan; place srcs.
__global__ __launch_bounds__(256) void k_binB(const unsigned int* __restrict__ tmp,
                                              const int* __restrict__ gcur,
                                              int* __restrict__ rowptr,
                                              float* __restrict__ dinv,
                                              int* __restrict__ srcs) {
  __shared__ int sbuf[256];
  __shared__ int hist[512];
  __shared__ int lofs[512];
  const int b = blockIdx.x;
  const int tid = threadIdx.x;
  // redundant exclusive scan of bucket counts
  int c = (tid < NBKT) ? gcur[tid] : 0;
  sbuf[tid] = c;
  __syncthreads();
#pragma unroll
  for (int off = 1; off < 256; off <<= 1) {
    int t = (tid >= off) ? sbuf[tid - off] : 0;
    __syncthreads();
    sbuf[tid] += t;
    __syncthreads();
  }
  const int total = sbuf[255];
  const int incl = sbuf[b];
  const int base_b = (b > 0) ? sbuf[b - 1] : 0;
  const int cntb = incl - base_b;
  if (b == 0 && tid == 0) rowptr[NN] = total;
  __syncthreads();
  hist[tid] = 0;
  hist[tid + 256] = 0;
  __syncthreads();
  const int tbeg = b * BCAP;
  const int tend = tbeg + cntb;
  for (int j = tbeg + tid; j < tend; j += 256) atomicAdd(&hist[tmp[j] & 511], 1);
  __syncthreads();
  int a0 = hist[2 * tid], a1 = hist[2 * tid + 1];
  int sv = a0 + a1;
  sbuf[tid] = sv;
  __syncthreads();
#pragma unroll
  for (int off = 1; off < 256; off <<= 1) {
    int t = (tid >= off) ? sbuf[tid - off] : 0;
    __syncthreads();
    sbuf[tid] += t;
    __syncthreads();
  }
  int excl = sbuf[tid] - sv;
  lofs[2 * tid] = excl;
  lofs[2 * tid + 1] = excl + a0;
  __syncthreads();
  for (int i = tid; i < 512; i += 256) {
    int node = (b << 9) + i;
    if (node < NN) {
      rowptr[node] = base_b + lofs[i];
      dinv[node] = rsqrtf((float)(hist[i] + 1));
    }
  }
  __syncthreads();
  for (int j = tbeg + tid; j < tend; j += 256) {
    unsigned v = tmp[j];
    int p = base_b + atomicAdd(&lofs[v & 511], 1);
    srcs[p] = (int)(v >> 9);
  }
}

// C[M,N] = A[M,128] @ W[128,N] via mfma_f32_16x16x32_f16.
// Epilogue scales row by dinv[row] (pre-scaled message table), fp16 out.
template <int N, bool AHALF>
__global__ __launch_bounds__(256) void k_gemm_mfma(const void* __restrict__ Av,
                                                   const _Float16* __restrict__ Wt,
                                                   const float* __restrict__ dinv,
                                                   _Float16* __restrict__ out, int M) {
  constexpr int NF = N / 16;
  __shared__ _Float16 As[64 * 136];
  __shared__ _Float16 Bs[N * 136];
  const int tid = threadIdx.x;
  const long long row0 = (long long)blockIdx.x * 64;
  if (AHALF) {
    const _Float16* A = (const _Float16*)Av;
#pragma unroll
    for (int t = 0; t < 4; ++t) {
      int i = tid + t * 256;
      int m = i >> 4, q = i & 15;
      long long row = row0 + m;
      uint4 v = make_uint4(0, 0, 0, 0);
      if (row < M) v = ((const uint4*)A)[row * 16 + q];
      *(uint4*)&As[m * 136 + q * 8] = v;
    }
  } else {
    const float* A = (const float*)Av;
#pragma unroll
    for (int t = 0; t < 8; ++t) {
      int i = tid + t * 256;
      int m = i >> 5, q = i & 31;
      long long row = row0 + m;
      float4 v = make_float4(0.f, 0.f, 0.f, 0.f);
      if (row < M) v = ((const float4*)A)[row * 32 + q];
      uint2 w2 = make_uint2(packh2(v.x, v.y), packh2(v.z, v.w));
      *(uint2*)&As[m * 136 + q * 4] = w2;
    }
  }
#pragma unroll
  for (int t = 0; t < N / 16; ++t) {
    int i = tid + t * 256;
    int n = i >> 4, q = i & 15;
    uint4 v = ((const uint4*)Wt)[i];
    *(uint4*)&Bs[n * 136 + q * 8] = v;
  }
  __syncthreads();
  const int lane = tid & 63;
  const int wrow = (tid >> 6) * 16;
  const int r = lane & 15, g = lane >> 4;
  f32x4 acc[NF] = {};
#pragma unroll
  for (int ks = 0; ks < 4; ++ks) {
    f16x8 av = *(const f16x8*)&As[(wrow + r) * 136 + ks * 32 + g * 8];
#pragma unroll
    for (int cf = 0; cf < NF; ++cf) {
      f16x8 bv = *(const f16x8*)&Bs[(cf * 16 + r) * 136 + ks * 32 + g * 8];
      acc[cf] = __builtin_amdgcn_mfma_f32_16x16x32_f16(av, bv, acc[cf], 0, 0, 0);
    }
  }
#pragma unroll
  for (int q = 0; q < 4; ++q) {
    long long row = row0 + wrow + g * 4 + q;
    if (row < M) {
      float sc = dinv[row];
#pragma unroll
      for (int cf = 0; cf < NF; ++cf)
        out[row * N + cf * 16 + r] = (_Float16)(sc * acc[cf][q]);
    }
  }
}

// Gather-reduce over pre-scaled table: out[d] = dd*(sum rows incl. self) + b.
// RELU16: relu + fp16 out (layer 1); else fp32 out (final).
template <int C, bool RELU16>
__global__ __launch_bounds__(256) void k_gather_s(const int* __restrict__ rowptr,
                                                  const int* __restrict__ srcs,
                                                  const float* __restrict__ dinv,
                                                  const _Float16* __restrict__ h,
                                                  const float* __restrict__ b,
                                                  void* __restrict__ outv) {
  constexpr int LPN = C / 8;
  constexpr int NPW = 64 / LPN;
  constexpr int NPB = NPW * 4;
  const int wave = threadIdx.x >> 6;
  const int lane = threadIdx.x & 63;
  const int grp = lane / LPN;
  const int li = lane % LPN;
  const int node = blockIdx.x * NPB + wave * NPW + grp;
  if (node >= NN) return;
  const float dd = dinv[node];
  float acc[8];
  {
    uint4 q = *(const uint4*)(h + (long long)node * C + li * 8);
    const __half2* p = (const __half2*)&q;
#pragma unroll
    for (int j = 0; j < 4; ++j) {
      float2 f = __half22float2(p[j]);
      acc[2 * j]     = f.x;
      acc[2 * j + 1] = f.y;
    }
  }
  const int beg = rowptr[node], end = rowptr[node + 1];
  int e = beg;
  for (; e + 4 <= end; e += 4) {
    int s0 = srcs[e], s1 = srcs[e + 1], s2 = srcs[e + 2], s3 = srcs[e + 3];
    uint4 q0 = *(const uint4*)(h + (long long)s0 * C + li * 8);
    uint4 q1 = *(const uint4*)(h + (long long)s1 * C + li * 8);
    uint4 q2 = *(const uint4*)(h + (long long)s2 * C + li * 8);
    uint4 q3 = *(const uint4*)(h + (long long)s3 * C + li * 8);
    add8(acc, q0);
    add8(acc, q1);
    add8(acc, q2);
    add8(acc, q3);
  }
  for (; e < end; ++e) {
    uint4 q0 = *(const uint4*)(h + (long long)srcs[e] * C + li * 8);
    add8(acc, q0);
  }
  const float4* b4 = (const float4*)b;
  float4 bb0 = b4[li * 2], bb1 = b4[li * 2 + 1];
  float o[8];
  o[0] = fmaf(dd, acc[0], bb0.x);
  o[1] = fmaf(dd, acc[1], bb0.y);
  o[2] = fmaf(dd, acc[2], bb0.z);
  o[3] = fmaf(dd, acc[3], bb0.w);
  o[4] = fmaf(dd, acc[4], bb1.x);
  o[5] = fmaf(dd, acc[5], bb1.y);
  o[6] = fmaf(dd, acc[6], bb1.z);
  o[7] = fmaf(dd, acc[7], bb1.w);
  if (RELU16) {
#pragma unroll
    for (int j = 0; j < 8; ++j) o[j] = fmaxf(o[j], 0.f);
    uint4 w;
    w.x = packh2(o[0], o[1]);
    w.y = packh2(o[2], o[3]);
    w.z = packh2(o[4], o[5]);
    w.w = packh2(o[6], o[7]);
    *(uint4*)((_Float16*)outv + (long long)node * C + li * 8) = w;
  } else {
    float4* op = (float4*)((float*)outv + (long long)node * C + li * 8);
    op[0] = make_float4(o[0], o[1], o[2], o[3]);
    op[1] = make_float4(o[4], o[5], o[6], o[7]);
  }
}

// ---------------- fallback (atomic scatter, fp32) kernels ----------------
__global__ void k_zero_i32(int* p, int n) {
  int i = blockIdx.x * 256 + threadIdx.x;
  if (i < n) p[i] = 0;
}

__global__ void k_detect_f(const int* __restrict__ e, int* flag, int E) {
  if (threadIdx.x == 0 && blockIdx.x == 0) {
    int n = E < 64 ? E : 64;
    int m = 1;
    for (int i = 0; i < n; ++i)
      if (e[2 * i + 1] != 0) { m = 0; break; }
    *flag = m;
  }
}

__global__ void k_deg_count(const int* __restrict__ e, const int* __restrict__ flag,
                            int* __restrict__ deg, int E) {
  int i = blockIdx.x * 256 + threadIdx.x;
  if (i >= E) return;
  int m = *flag;
  int d = m ? e[2 * (E + i)] : e[E + i];
  atomicAdd(&deg[d], 1);
}

__global__ void k_dinv_f(const int* __restrict__ deg, float* __restrict__ dinv) {
  int i = blockIdx.x * 256 + threadIdx.x;
  if (i < NN) dinv[i] = rsqrtf((float)(deg[i] + 1));
}

template <int N, bool RELU>
__global__ __launch_bounds__(256) void k_gemm_v(const float* __restrict__ A,
                                                const float* __restrict__ W,
                                                float* __restrict__ out, int M) {
  constexpr int K4 = 32;
  constexpr int N4 = N / 4;
  constexpr int CG = N4;
  constexpr int ROWS = (256 / CG) * 4;
  __shared__ float4 Wl[128 * N4];
  __shared__ float4 Xl[ROWS * K4];
  const int tid = threadIdx.x;
  const float4* W4 = (const float4*)W;
  for (int i = tid; i < 128 * N4; i += 256) Wl[i] = W4[i];
  const long long row0 = (long long)blockIdx.x * ROWS;
  const float4* A4 = (const float4*)A;
  for (int i = tid; i < ROWS * K4; i += 256) {
    int r = i >> 5;
    long long row = row0 + r;
    float4 v = make_float4(0.f, 0.f, 0.f, 0.f);
    if (row < M) v = A4[row * K4 + (i & 31)];
    if (RELU) {
      v.x = fmaxf(v.x, 0.f); v.y = fmaxf(v.y, 0.f);
      v.z = fmaxf(v.z, 0.f); v.w = fmaxf(v.w, 0.f);
    }
    Xl[i] = v;
  }
  __syncthreads();
  const int c = tid % CG;
  const int rb = (tid / CG) * 4;
  float4 a0 = make_float4(0, 0, 0, 0), a1 = a0, a2 = a0, a3 = a0;
#pragma unroll 4
  for (int k4 = 0; k4 < K4; ++k4) {
    float4 w0 = Wl[(k4 * 4 + 0) * N4 + c];
    float4 w1 = Wl[(k4 * 4 + 1) * N4 + c];
    float4 w2 = Wl[(k4 * 4 + 2) * N4 + c];
    float4 w3 = Wl[(k4 * 4 + 3) * N4 + c];
    float4 x0 = Xl[(rb + 0) * K4 + k4];
    float4 x1 = Xl[(rb + 1) * K4 + k4];
    float4 x2 = Xl[(rb + 2) * K4 + k4];
    float4 x3 = Xl[(rb + 3) * K4 + k4];
    fma4(a0, x0.x, w0); fma4(a0, x0.y, w1); fma4(a0, x0.z, w2); fma4(a0, x0.w, w3);
    fma4(a1, x1.x, w0); fma4(a1, x1.y, w1); fma4(a1, x1.z, w2); fma4(a1, x1.w, w3);
    fma4(a2, x2.x, w0); fma4(a2, x2.y, w1); fma4(a2, x2.z, w2); fma4(a2, x2.w, w3);
    fma4(a3, x3.x, w0); fma4(a3, x3.y, w1); fma4(a3, x3.z, w2); fma4(a3, x3.w, w3);
  }
  float4* O4 = (float4*)out;
  long long row = row0 + rb;
  if (row + 0 < M) O4[(row + 0) * N4 + c] = a0;
  if (row + 1 < M) O4[(row + 1) * N4 + c] = a1;
  if (row + 2 < M) O4[(row + 2) * N4 + c] = a2;
  if (row + 3 < M) O4[(row + 3) * N4 + c] = a3;
}

template <int C>
__global__ void k_self_bias(const float* __restrict__ h, const float* __restrict__ dinv,
                            const float* __restrict__ b, float* __restrict__ out) {
  constexpr int C4 = C / 4;
  int gid = blockIdx.x * 256 + threadIdx.x;
  if (gid >= NN * C4) return;
  int node = gid / C4;
  int cq = gid % C4;
  float di = dinv[node];
  float sc = di * di;
  float4 v = ((const float4*)h)[gid];
  float4 bb = ((const float4*)b)[cq];
  float4 o;
  o.x = fmaf(v.x, sc, bb.x);
  o.y = fmaf(v.y, sc, bb.y);
  o.z = fmaf(v.z, sc, bb.z);
  o.w = fmaf(v.w, sc, bb.w);
  ((float4*)out)[gid] = o;
}

template <int C>
__global__ void k_scatter(const int* __restrict__ e, const int* __restrict__ flag,
                          const float* __restrict__ dinv, const float* __restrict__ h,
                          float* __restrict__ out, int E) {
  constexpr int TPE = C / 4;
  long long gid = (long long)blockIdx.x * blockDim.x + threadIdx.x;
  int ei = (int)(gid / TPE);
  int cq = (int)(gid % TPE);
  if (ei >= E) return;
  int m = *flag;
  int s, d;
  if (m) { s = e[2 * ei]; d = e[2 * (E + ei)]; }
  else   { s = e[ei];     d = e[E + ei]; }
  float nrm = dinv[s] * dinv[d];
  float4 v = ((const float4*)h)[(long long)s * TPE + cq];
  float* op = out + (long long)d * C + (long long)cq * 4;
  unsafeAtomicAdd(op + 0, v.x * nrm);
  unsafeAtomicAdd(op + 1, v.y * nrm);
  unsafeAtomicAdd(op + 2, v.z * nrm);
  unsafeAtomicAdd(op + 3, v.w * nrm);
}

extern "C" void kernel_launch(void* const* d_in, const int* in_sizes, int n_in,
                              void* d_out, int out_size, void* d_ws, size_t ws_size,
                              hipStream_t stream) {
  const float* x  = (const float*)d_in[0];
  const int*   e  = (const int*)d_in[1];
  const float* W1 = (const float*)d_in[2];
  const float* b1 = (const float*)d_in[3];
  const float* W2 = (const float*)d_in[4];
  const float* b2 = (const float*)d_in[5];
  float* out = (float*)d_out;
  const int E = in_sizes[1] / 2;

  char* ws = (char*)d_ws;
  const size_t o_flag    = 0;         // 16
  const size_t o_dinv    = 16;        // 400,000
  const size_t o_rowptr  = 400016;    // 400,004 (NN+1)
  const size_t o_gcur    = 800032;    // 784
  const size_t o_tmp     = 800832;    // 196*16384*4 = 12,845,056
  const size_t o_srcs    = 13645888;  // 6,400,000
  const size_t o_wt1     = 20045888;  // 32,768
  const size_t o_wt2     = 20078656;  // 16,384
  const size_t o_h       = 20095040;  // fp16 h: 25,600,000
  const size_t o_out1    = 45695040;  // fp16 out1: 25,600,000
  const size_t need_csr  = 71295040;

  int*      flag   = (int*)(ws + o_flag);
  float*    dinv   = (float*)(ws + o_dinv);
  int*      rowptr = (int*)(ws + o_rowptr);
  int*      gcur   = (int*)(ws + o_gcur);
  unsigned* tmp    = (unsigned*)(ws + o_tmp);
  int*      srcs   = (int*)(ws + o_srcs);
  _Float16* wt1    = (_Float16*)(ws + o_wt1);
  _Float16* wt2    = (_Float16*)(ws + o_wt2);
  _Float16* hh     = (_Float16*)(ws + o_h);
  _Float16* out1   = (_Float16*)(ws + o_out1);

  if (ws_size >= need_csr) {
    // ---- CSR gather path: fused binned build, pre-scaled fp16, MFMA ----
    const int nA = (E + 4095) / 4096;
    hipMemsetAsync(gcur, 0, NBKT * sizeof(int), stream);
    k_binA<<<nA + 96, 256, 0, stream>>>(e, W1, W2, wt1, wt2, gcur, tmp, E, nA);
    k_binB<<<NBKT, 256, 0, stream>>>(tmp, gcur, rowptr, dinv, srcs);

    k_gemm_mfma<128, false><<<(NN + 63) / 64, 256, 0, stream>>>(x, wt1, dinv, hh, NN);
    k_gather_s<128, true><<<(NN + 15) / 16, 256, 0, stream>>>(rowptr, srcs, dinv, hh, b1, out1);

    k_gemm_mfma<64, true><<<(NN + 63) / 64, 256, 0, stream>>>(out1, wt2, dinv, hh, NN);
    k_gather_s<64, false><<<(NN + 31) / 32, 256, 0, stream>>>(rowptr, srcs, dinv, hh, b2, out);
  } else {
    // ---- fallback: fp32 atomic scatter path ----
    int*   deg   = (int*)(ws + 400016);
    float* hF    = (float*)(ws + (1 << 20));
    float* out1F = (float*)(ws + (1 << 20) + 51200000);
    k_detect_f<<<1, 64, 0, stream>>>(e, flag, E);
    k_zero_i32<<<(NN + 255) / 256, 256, 0, stream>>>(deg, NN);
    k_deg_count<<<(E + 255) / 256, 256, 0, stream>>>(e, flag, deg, E);
    k_dinv_f<<<(NN + 255) / 256, 256, 0, stream>>>(deg, dinv);
    k_gemm_v<128, false><<<(NN + 31) / 32, 256, 0, stream>>>(x, W1, hF, NN);
    k_self_bias<128><<<(NN * 32 + 255) / 256, 256, 0, stream>>>(hF, dinv, b1, out1F);
    long long tot1 = (long long)E * 32;
    k_scatter<128><<<(int)((tot1 + 255) / 256), 256, 0, stream>>>(e, flag, dinv, hF, out1F, E);
    k_gemm_v<64, true><<<(NN + 63) / 64, 256, 0, stream>>>(out1F, W2, hF, NN);
    k_self_bias<64><<<(NN * 16 + 255) / 256, 256, 0, stream>>>(hF, dinv, b2, out);
    long long tot2 = (long long)E * 16;
    k_scatter<64><<<(int)((tot2 + 255) / 256), 256, 0, stream>>>(e, flag, dinv, hF, out, E);
  }
}